// Round 14
// baseline (2486.127 us; speedup 1.0000x reference)
//
#include <hip/hip_runtime.h>
#include <math.h>

#define L_ 8
#define H_ 16
#define E_ 1024
#define V_ 32000
#define B_ 4
#define T_ 1024
#define HS_ 64
#define M_ 4096   // B*T
#define QKVS_ 3072  // fused qkv row stride

typedef __attribute__((ext_vector_type(8))) short short8;
typedef __attribute__((ext_vector_type(4))) float f32x4;

__device__ __forceinline__ unsigned short f2bf(float f) {
  unsigned int u = __builtin_bit_cast(unsigned int, f);
  u += 0x7fffu + ((u >> 16) & 1u);          // RNE
  return (unsigned short)(u >> 16);
}
__device__ __forceinline__ float bf2f(unsigned short u) {
  unsigned int v = ((unsigned int)u) << 16;
  return __builtin_bit_cast(float, v);
}

// ---------------------------------------------------------------- embed (fp32 x)
__global__ __launch_bounds__(256) void k_embed(
    const int* __restrict__ idx, const float* __restrict__ tok,
    const float* __restrict__ pos, float* __restrict__ x) {
  int bt = blockIdx.x;
  int t  = bt & (T_ - 1);
  int token = idx[bt];
  const float4* te = (const float4*)(tok + (size_t)token * E_);
  const float4* pe = (const float4*)(pos + (size_t)t * E_);
  float4* xo = (float4*)(x + (size_t)bt * E_);
  int i = threadIdx.x;
  float4 a = te[i], b = pe[i];
  xo[i] = make_float4(a.x + b.x, a.y + b.y, a.z + b.z, a.w + b.w);
}

// ---------------------------------------------------------------- weight transpose+convert (vectorized)
__global__ __launch_bounds__(256) void k_wt(
    const float* __restrict__ W, unsigned short* __restrict__ WT,
    int K, int N, size_t ss, size_t ds) {
  __shared__ unsigned short t[64][68];   // 136B rows: 8B-aligned ushort4 everywhere
  const float* Ws = W + (size_t)blockIdx.z * ss;
  unsigned short* Wd = WT + (size_t)blockIdx.z * ds;
  int n0 = blockIdx.x * 64, k0 = blockIdx.y * 64;
  int tid = threadIdx.x;
  int c4 = (tid & 15) * 4, r16 = tid >> 4;
  #pragma unroll
  for (int i = 0; i < 4; ++i) {
    int kr = i * 16 + r16;
    float4 v = *(const float4*)&Ws[(size_t)(k0 + kr) * N + n0 + c4];
    ushort4 pk;
    pk.x = f2bf(v.x); pk.y = f2bf(v.y); pk.z = f2bf(v.z); pk.w = f2bf(v.w);
    *(ushort4*)&t[kr][c4] = pk;
  }
  __syncthreads();
  #pragma unroll
  for (int i = 0; i < 4; ++i) {
    int nr = i * 16 + r16;
    ushort4 o;
    o.x = t[c4 + 0][nr]; o.y = t[c4 + 1][nr];
    o.z = t[c4 + 2][nr]; o.w = t[c4 + 3][nr];
    *(ushort4*)&Wd[(size_t)(n0 + nr) * K + k0 + c4] = o;
  }
}

// ---------------------------------------------------------------- layernorm (fp32 in, bf16 out)
__device__ __forceinline__ float blk_sum256(float v, float* red) {
  #pragma unroll
  for (int o = 1; o < 64; o <<= 1) v += __shfl_xor(v, o);
  int wid = threadIdx.x >> 6, lane = threadIdx.x & 63;
  if (lane == 0) red[wid] = v;
  __syncthreads();
  v = red[0] + red[1] + red[2] + red[3];
  __syncthreads();
  return v;
}

__global__ __launch_bounds__(256) void k_ln_bf(
    const float* __restrict__ X, const float* __restrict__ g,
    const float* __restrict__ b, unsigned short* __restrict__ Y) {
  __shared__ float red[4];
  int row = blockIdx.x;
  int i = threadIdx.x;
  float4 xv = ((const float4*)(X + (size_t)row * E_))[i];
  float s = xv.x + xv.y + xv.z + xv.w;
  s = blk_sum256(s, red);
  float mean = s * (1.0f / E_);
  float dx = xv.x - mean, dy = xv.y - mean, dz = xv.z - mean, dw = xv.w - mean;
  float vs = dx*dx + dy*dy + dz*dz + dw*dw;
  vs = blk_sum256(vs, red);
  float rstd = rsqrtf(vs * (1.0f / E_) + 1e-5f);
  float4 gv = ((const float4*)g)[i];
  float4 bv = ((const float4*)b)[i];
  ushort4 o;
  o.x = f2bf(dx * rstd * gv.x + bv.x);
  o.y = f2bf(dy * rstd * gv.y + bv.y);
  o.z = f2bf(dz * rstd * gv.z + bv.z);
  o.w = f2bf(dw * rstd * gv.w + bv.w);
  ((ushort4*)(Y + (size_t)row * E_))[i] = o;
}

// ---------------------------------------------------------------- fused split-K reduce + residual + next-LN
// x[row] += sum4(bf16 partials) + bias; then LN(x[row]) with (g,b) -> hb (bf16).
__global__ __launch_bounds__(256) void k_red4ln(
    const unsigned short* __restrict__ p, const float* __restrict__ bias,
    float* __restrict__ xf, const float* __restrict__ g,
    const float* __restrict__ b, unsigned short* __restrict__ hb) {
  __shared__ float red[4];
  const int ME = M_ * E_;
  int row = blockIdx.x;
  int tid = threadIdx.x;
  int i = row * E_ + tid * 4;
  ushort4 a  = *(const ushort4*)(p + i);
  ushort4 b2 = *(const ushort4*)(p + ME + i);
  ushort4 c  = *(const ushort4*)(p + 2 * ME + i);
  ushort4 d  = *(const ushort4*)(p + 3 * ME + i);
  float4 bv = *(const float4*)(bias + tid * 4);
  float4 x  = *(float4*)(xf + i);
  x.x += bf2f(a.x) + bf2f(b2.x) + bf2f(c.x) + bf2f(d.x) + bv.x;
  x.y += bf2f(a.y) + bf2f(b2.y) + bf2f(c.y) + bf2f(d.y) + bv.y;
  x.z += bf2f(a.z) + bf2f(b2.z) + bf2f(c.z) + bf2f(d.z) + bv.z;
  x.w += bf2f(a.w) + bf2f(b2.w) + bf2f(c.w) + bf2f(d.w) + bv.w;
  *(float4*)(xf + i) = x;
  float s = x.x + x.y + x.z + x.w;
  s = blk_sum256(s, red);
  float mean = s * (1.0f / E_);
  float dx = x.x - mean, dy = x.y - mean, dz = x.z - mean, dw = x.w - mean;
  float vs = dx*dx + dy*dy + dz*dz + dw*dw;
  vs = blk_sum256(vs, red);
  float rstd = rsqrtf(vs * (1.0f / E_) + 1e-5f);
  float4 gv = ((const float4*)g)[tid];
  float4 lb = ((const float4*)b)[tid];
  ushort4 o;
  o.x = f2bf(dx * rstd * gv.x + lb.x);
  o.y = f2bf(dy * rstd * gv.y + lb.y);
  o.z = f2bf(dz * rstd * gv.z + lb.z);
  o.w = f2bf(dw * rstd * gv.w + lb.w);
  ((ushort4*)(hb + (size_t)row * E_))[tid] = o;
}

#define GLDS(src, dst) __builtin_amdgcn_global_load_lds( \
    (const __attribute__((address_space(1))) void*)(src), \
    (__attribute__((address_space(3))) void*)(dst), 16, 0, 0)

#define BAR() do { asm volatile("" ::: "memory"); __builtin_amdgcn_s_barrier(); \
                   asm volatile("" ::: "memory"); } while (0)

// ---------------------------------------------------------------- 256xBN 8-phase bf16 GEMM (BK=64)
// DEC: 0 = m-fastest, 1 = LM head (msub8-fastest), 2 = split-K=4 partials.
template<int OT, bool RELU, int DEC, int NF>
__global__ __launch_bounds__(512, 2) void k_gemm_256(
    const unsigned short* __restrict__ A, const unsigned short* __restrict__ BT,
    const float* __restrict__ bias, void* __restrict__ Cout, int N, int K, int Kstr) {
  constexpr int BUFA = 16384;        // 256*64
  constexpr int BUFB = NF * 4096;    // BN*64
  constexpr int BN = NF * 64;
  __shared__ __attribute__((aligned(16))) unsigned short As[2 * BUFA];
  __shared__ __attribute__((aligned(16))) unsigned short Bs[2 * BUFB];
  int tid = threadIdx.x;
  int lane = tid & 63, w = tid >> 6;           // 8 waves
  int lr = lane & 15, lq = (lane >> 4) & 3;
  int wm = w >> 2, wn = w & 3;                 // 2 x 4 wave grid

  // bijective XCD swizzle (m204)
  int nwg = gridDim.x, orig = blockIdx.x;
  int qq = nwg >> 3, rr = nwg & 7;
  int xcd = orig & 7, lid = orig >> 3;
  int wg = (xcd < rr ? xcd * (qq + 1) : rr * (qq + 1) + (xcd - rr) * qq) + lid;
  int m0, n0, kofs = 0;
  size_t cofs = 0;
  if constexpr (DEC == 0) { m0 = (wg & 15) * 256; n0 = (wg >> 4) * BN; }
  else if constexpr (DEC == 1) {
    int nbn = N / BN;
    int msub = wg & 7;
    int rest = wg >> 3;
    int nb = rest % nbn;
    int msup = rest / nbn;
    m0 = (msup * 8 + msub) * 256;
    n0 = nb * BN;
  } else {
    int inner = wg & 63;
    m0 = (inner & 15) * 256; n0 = (inner >> 4) * BN;
    int ks = wg >> 6;
    kofs = ks * K;
    cofs = (size_t)ks * M_ * (size_t)N;
  }

  // staging: chunk swizzle c8_src = (lane&7) ^ (lane>>3); dest linear
  int srow = w * 8 + (lane >> 3);
  int skoff = ((lane & 7) ^ (lane >> 3)) * 8;
  const unsigned short* aS = A + (size_t)(m0 + srow) * Kstr + kofs + skoff;
  const unsigned short* bS = BT + (size_t)(n0 + srow) * Kstr + kofs + skoff;

#define STG_A1(bo, g, tt) GLDS(aS + (size_t)((g) * 64) * Kstr + (tt) * 64, \
                               &As[(bo) + (((g) * 64) << 6) + (w << 9)])
#define STG_B1(bo, g, tt) GLDS(bS + (size_t)((g) * 64) * Kstr + (tt) * 64, \
                               &Bs[(bo) + (((g) * 64) << 6) + (w << 9)])
#define LDA_(dst, mh, ks) { _Pragma("unroll") for (int m_ = 0; m_ < 4; ++m_) \
  dst[m_] = *(const short8*)&As[soA + ((wm * 128 + (mh) * 64 + m_ * 16 + lr) << 6) + ((((ks) * 4 + lq) ^ (lr & 7)) << 3)]; }
#define LDB_(dst, ks) { _Pragma("unroll") for (int n_ = 0; n_ < NF; ++n_) \
  dst[n_] = *(const short8*)&Bs[soB + ((wn * (16 * NF) + n_ * 16 + lr) << 6) + ((((ks) * 4 + lq) ^ (lr & 7)) << 3)]; }
#define MMA(afr, mofs) do { __builtin_amdgcn_s_setprio(1); \
  _Pragma("unroll") for (int m_ = 0; m_ < 4; ++m_) { \
    _Pragma("unroll") for (int n_ = 0; n_ < NF; ++n_) \
      acc[(mofs) + m_][n_] = __builtin_amdgcn_mfma_f32_16x16x32_bf16(afr[m_], bfr[n_], acc[(mofs) + m_][n_], 0, 0, 0); } \
  __builtin_amdgcn_s_setprio(0); } while (0)

  f32x4 acc[8][NF] = {};
  const int NT = K >> 6;

  // prologue: tile0 full (4+NF loads) + B(t1) g0,g1 -> vmcnt(2)
  #pragma unroll
  for (int g = 0; g < 4; ++g) STG_A1(0, g, 0);
  #pragma unroll
  for (int g = 0; g < NF; ++g) STG_B1(0, g, 0);
  if (NT > 1) {
    STG_B1(BUFB, 0, 1); STG_B1(BUFB, 1, 1);
    asm volatile("s_waitcnt vmcnt(2)" ::: "memory");
  } else {
    asm volatile("s_waitcnt vmcnt(0)" ::: "memory");
  }
  BAR();

  for (int t = 0; t < NT; ++t) {
    const int soA = (t & 1) * BUFA, soB = (t & 1) * BUFB;
    const int nbA = ((t + 1) & 1) * BUFA, nbB = ((t + 1) & 1) * BUFB;
    short8 af0[4], af1[4], bfr[NF];
    // ---- P0: stage B-hi(t+1) -> idle
    LDA_(af0, 0, 0);
    LDB_(bfr, 0);
    if (t + 1 < NT) {
      STG_B1(nbB, 2, t + 1);
      if constexpr (NF == 4) STG_B1(nbB, 3, t + 1);
    }
    BAR(); MMA(af0, 0); BAR();
    // ---- P1: stage A-lo(t+1) -> idle
    LDA_(af1, 1, 0);
    if (t + 1 < NT) { STG_A1(nbA, 0, t + 1); STG_A1(nbA, 1, t + 1); }
    BAR(); MMA(af1, 4); BAR();
    // ---- P2: stage A-hi(t+1) -> idle
    LDA_(af0, 0, 1);
    LDB_(bfr, 1);
    if (t + 1 < NT) { STG_A1(nbA, 2, t + 1); STG_A1(nbA, 3, t + 1); }
    BAR(); MMA(af0, 0); BAR();
    // ---- P3: stage B-lo(t+2) -> current buffer B region (dead after P2)
    LDA_(af1, 1, 1);
    if (t + 2 < NT) { STG_B1(soB, 0, t + 2); STG_B1(soB, 1, t + 2); }
    BAR(); MMA(af1, 4);
    if (t + 2 < NT) { asm volatile("s_waitcnt vmcnt(2)" ::: "memory"); }
    else            { asm volatile("s_waitcnt vmcnt(0)" ::: "memory"); }
    BAR();
  }

  #pragma unroll
  for (int m = 0; m < 8; ++m) {
    #pragma unroll
    for (int n = 0; n < NF; ++n) {
      int col = n0 + wn * (16 * NF) + n * 16 + lr;
      float bv = bias ? bias[col] : 0.0f;
      #pragma unroll
      for (int i = 0; i < 4; ++i) {
        size_t row = (size_t)(m0 + wm * 128 + m * 16 + lq * 4 + i);
        float v = acc[m][n][i] + bv;
        if (RELU) v = fmaxf(v, 0.0f);
        if (OT == 0) ((float*)Cout)[cofs + row * N + col] = v;
        else ((unsigned short*)Cout)[cofs + row * N + col] = f2bf(v);
      }
    }
  }
#undef STG_A1
#undef STG_B1
#undef LDA_
#undef LDB_
#undef MMA
}

// ---------------------------------------------------------------- legacy GEMM (fp32 B) for LM fallback
template<int OT, bool RELU, bool RES>
__global__ __launch_bounds__(256) void k_gemm_bf(
    const unsigned short* __restrict__ A, const float* __restrict__ W,
    const float* __restrict__ bias, const float* __restrict__ R,
    void* __restrict__ Cout, int M, int N, int K) {
  __shared__ unsigned short As[128][40];
  __shared__ unsigned short Bs[128][40];
  int tid = threadIdx.x;
  int lane = tid & 63, wid = tid >> 6;
  int m0 = blockIdx.x * 128, n0 = blockIdx.y * 128;
  int wr = (wid >> 1) * 64, wc = (wid & 1) * 64;
  f32x4 acc[4][4] = {};
  int a_row = tid >> 1, a_koff = (tid & 1) * 16;
  int b_nb = tid & 31, b_kb = (tid >> 5) * 4;
  int lr = lane & 15, lq = lane >> 4;
  for (int k0 = 0; k0 < K; k0 += 32) {
    const unsigned short* ap = A + (size_t)(m0 + a_row) * K + k0 + a_koff;
    uint4 av0 = *(const uint4*)ap;
    uint4 av1 = *(const uint4*)(ap + 8);
    float wv[4][4];
    #pragma unroll
    for (int dk = 0; dk < 4; ++dk) {
      const float* wrow = W + (size_t)(k0 + b_kb + dk) * N + n0 + b_nb;
      #pragma unroll
      for (int j = 0; j < 4; ++j) wv[j][dk] = wrow[32 * j];
    }
    __syncthreads();
    *(uint4*)&As[a_row][a_koff]     = av0;
    *(uint4*)&As[a_row][a_koff + 8] = av1;
    #pragma unroll
    for (int j = 0; j < 4; ++j) {
      ushort4 pk;
      pk.x = f2bf(wv[j][0]); pk.y = f2bf(wv[j][1]);
      pk.z = f2bf(wv[j][2]); pk.w = f2bf(wv[j][3]);
      *(ushort4*)&Bs[b_nb + 32 * j][b_kb] = pk;
    }
    __syncthreads();
    short8 af[4], bf[4];
    #pragma unroll
    for (int m = 0; m < 4; ++m) af[m] = *(const short8*)&As[wr + m * 16 + lr][lq * 8];
    #pragma unroll
    for (int n = 0; n < 4; ++n) bf[n] = *(const short8*)&Bs[wc + n * 16 + lr][lq * 8];
    #pragma unroll
    for (int m = 0; m < 4; ++m)
      #pragma unroll
      for (int n = 0; n < 4; ++n)
        acc[m][n] = __builtin_amdgcn_mfma_f32_16x16x32_bf16(af[m], bf[n], acc[m][n], 0, 0, 0);
  }
  #pragma unroll
  for (int m = 0; m < 4; ++m) {
    #pragma unroll
    for (int n = 0; n < 4; ++n) {
      int col = n0 + wc + n * 16 + lr;
      float bv = bias ? bias[col] : 0.0f;
      #pragma unroll
      for (int i = 0; i < 4; ++i) {
        size_t row = (size_t)(m0 + wr + m * 16 + lq * 4 + i);
        float v = acc[m][n][i] + bv;
        if (RELU) v = fmaxf(v, 0.0f);
        if (RES)  v += R[row * N + col];
        if (OT == 0) ((float*)Cout)[row * N + col] = v;
        else ((unsigned short*)Cout)[row * N + col] = f2bf(v);
      }
    }
  }
}

// ---------------------------------------------------------------- flash attention (bf16 MFMA)
__global__ __launch_bounds__(256) void k_fattn(
    const unsigned short* __restrict__ QKV, unsigned short* __restrict__ O) {
  __shared__ unsigned short Ks[64][72];
  __shared__ unsigned short Vs[64][74];
  __shared__ unsigned short Pl[4][32][72];
  int tid = threadIdx.x;
  int lane = tid & 63, wid = tid >> 6;
  int lr = lane & 15, lq = lane >> 4;
  int qt = blockIdx.x, bh = blockIdx.y;
  int b = bh >> 4, h = bh & 15;
  size_t base = ((size_t)b * T_) * QKVS_ + h * HS_;
  int q0w = qt * 128 + wid * 32;

  short8 qf[2][2];
  #pragma unroll
  for (int g = 0; g < 2; ++g)
    #pragma unroll
    for (int s = 0; s < 2; ++s)
      qf[g][s] = *(const short8*)(QKV + base + (size_t)(q0w + g * 16 + lr) * QKVS_ + s * 32 + lq * 8);

  f32x4 o_acc[2][4] = {};
  float mrun[2][4], lrun[2][4];
  #pragma unroll
  for (int g = 0; g < 2; ++g)
    #pragma unroll
    for (int i = 0; i < 4; ++i) { mrun[g][i] = -1e30f; lrun[g][i] = 0.0f; }
  const float sc = 0.03125f * 1.44269504f;
  int r = tid >> 2, cc = (tid & 3) * 16;
  int ntiles = 2 * qt + 2;

  uint4 kA0, kA1, vA0, vA1;
  {
    const unsigned short* kp = QKV + base + 1024 + (size_t)r * QKVS_ + cc;
    kA0 = *(const uint4*)kp; kA1 = *(const uint4*)(kp + 8);
    vA0 = *(const uint4*)(kp + 1024); vA1 = *(const uint4*)(kp + 1032);
  }

  for (int t = 0; t < ntiles; ++t) {
    __syncthreads();                         // prev tile's LDS reads done
    *(uint4*)&Ks[r][cc] = kA0;
    *(uint4*)&Ks[r][cc + 8] = kA1;
    unsigned short vt[16];
    *(uint4*)&vt[0] = vA0; *(uint4*)&vt[8] = vA1;
    #pragma unroll
    for (int j = 0; j < 16; ++j) Vs[cc + j][r] = vt[j];
    __syncthreads();                         // staging visible
    if (t + 1 < ntiles) {                    // T14: hide next-tile HBM under compute
      const unsigned short* kp = QKV + base + 1024 + (size_t)((t + 1) * 64 + r) * QKVS_ + cc;
      kA0 = *(const uint4*)kp; kA1 = *(const uint4*)(kp + 8);
      vA0 = *(const uint4*)(kp + 1024); vA1 = *(const uint4*)(kp + 1032);
    }

    f32x4 sa[2][4] = {};
    #pragma unroll
    for (int nt = 0; nt < 4; ++nt)
      #pragma unroll
      for (int s = 0; s < 2; ++s) {
        short8 kf = *(const short8*)&Ks[nt * 16 + lr][s * 32 + lq * 8];
        sa[0][nt] = __builtin_amdgcn_mfma_f32_16x16x32_bf16(qf[0][s], kf, sa[0][nt], 0, 0, 0);
        sa[1][nt] = __builtin_amdgcn_mfma_f32_16x16x32_bf16(qf[1][s], kf, sa[1][nt], 0, 0, 0);
      }

    bool diag = (t >= 2 * qt);
    float p[2][4][4];
    #pragma unroll
    for (int g = 0; g < 2; ++g)
      #pragma unroll
      for (int nt = 0; nt < 4; ++nt)
        #pragma unroll
        for (int i = 0; i < 4; ++i) {
          float v = sa[g][nt][i] * sc;
          if (diag && (t * 64 + nt * 16 + lr > q0w + g * 16 + lq * 4 + i)) v = -1e30f;
          p[g][nt][i] = v;
        }
    #pragma unroll
    for (int g = 0; g < 2; ++g)
      #pragma unroll
      for (int i = 0; i < 4; ++i) {
        float v = fmaxf(fmaxf(p[g][0][i], p[g][1][i]), fmaxf(p[g][2][i], p[g][3][i]));
        #pragma unroll
        for (int o = 1; o < 16; o <<= 1) v = fmaxf(v, __shfl_xor(v, o));
        if (v > mrun[g][i] + 10.0f) {        // T13 defer-max (log2 units; P <= 2^10)
          float corr = __builtin_amdgcn_exp2f(mrun[g][i] - v);
          mrun[g][i] = v;
          lrun[g][i] *= corr;
          #pragma unroll
          for (int dn = 0; dn < 4; ++dn) o_acc[g][dn][i] *= corr;
        }
        float mn = mrun[g][i];
        float ps = 0.0f;
        #pragma unroll
        for (int nt = 0; nt < 4; ++nt) {
          float pe = __builtin_amdgcn_exp2f(p[g][nt][i] - mn);
          p[g][nt][i] = pe;
          ps += pe;
        }
        lrun[g][i] += ps;
      }
    // P -> per-wave LDS transpose; intra-wave DS ordering suffices (no barrier)
    #pragma unroll
    for (int g = 0; g < 2; ++g)
      #pragma unroll
      for (int nt = 0; nt < 4; ++nt)
        #pragma unroll
        for (int i = 0; i < 4; ++i)
          Pl[wid][g * 16 + lq * 4 + i][nt * 16 + lr] = f2bf(p[g][nt][i]);

    #pragma unroll
    for (int s = 0; s < 2; ++s) {
      short8 pa0 = *(const short8*)&Pl[wid][lr][s * 32 + lq * 8];
      short8 pa1 = *(const short8*)&Pl[wid][16 + lr][s * 32 + lq * 8];
      #pragma unroll
      for (int dn = 0; dn < 4; ++dn) {
        short8 vf = *(const short8*)&Vs[dn * 16 + lr][s * 32 + lq * 8];
        o_acc[0][dn] = __builtin_amdgcn_mfma_f32_16x16x32_bf16(pa0, vf, o_acc[0][dn], 0, 0, 0);
        o_acc[1][dn] = __builtin_amdgcn_mfma_f32_16x16x32_bf16(pa1, vf, o_acc[1][dn], 0, 0, 0);
      }
    }
  }

  #pragma unroll
  for (int g = 0; g < 2; ++g)
    #pragma unroll
    for (int i = 0; i < 4; ++i) {
      float v = lrun[g][i];
      #pragma unroll
      for (int o = 1; o < 16; o <<= 1) v += __shfl_xor(v, o);
      lrun[g][i] = 1.0f / v;
    }
  #pragma unroll
  for (int g = 0; g < 2; ++g)
    #pragma unroll
    for (int dn = 0; dn < 4; ++dn)
      #pragma unroll
      for (int i = 0; i < 4; ++i) {
        size_t row = (size_t)(b * T_) + q0w + g * 16 + lq * 4 + i;
        O[row * E_ + h * HS_ + dn * 16 + lr] = f2bf(o_acc[g][dn][i] * lrun[g][i]);
      }
}

// ---------------------------------------------------------------- launch
extern "C" void kernel_launch(void* const* d_in, const int* in_sizes, int n_in,
                              void* d_out, int out_size, void* d_ws, size_t ws_size,
                              hipStream_t stream) {
  const int*   idx  = (const int*)d_in[0];
  const float* tok  = (const float*)d_in[1];
  const float* pos  = (const float*)d_in[2];
  const float* ln1g = (const float*)d_in[3];
  const float* ln1b = (const float*)d_in[4];
  const float* Wq   = (const float*)d_in[5];
  const float* Wk   = (const float*)d_in[6];
  const float* Wv   = (const float*)d_in[7];
  const float* Wo   = (const float*)d_in[8];
  const float* bo   = (const float*)d_in[9];
  const float* ln2g = (const float*)d_in[10];
  const float* ln2b = (const float*)d_in[11];
  const float* W1   = (const float*)d_in[12];
  const float* b1   = (const float*)d_in[13];
  const float* W2   = (const float*)d_in[14];
  const float* b2   = (const float*)d_in[15];
  const float* lnfg = (const float*)d_in[16];
  const float* lnfb = (const float*)d_in[17];
  const float* Wlm  = (const float*)d_in[18];
  const float* blm  = (const float*)d_in[19];

  char* scr = (char*)d_out;
  const size_t MB = 1024 * 1024;
  float*          xf    = (float*)(scr);                      // 16MB
  unsigned short* qkvb  = (unsigned short*)(scr + 16 * MB);   // 24MB
  unsigned short* ob    = (unsigned short*)(scr + 40 * MB);   // 8MB
  unsigned short* mh    = (unsigned short*)(scr + 48 * MB);   // 32MB
  unsigned short* wqkvT = (unsigned short*)(scr + 80 * MB);   // 48MB
  unsigned short* woT   = (unsigned short*)(scr + 128 * MB);  // 16MB
  unsigned short* w1T   = (unsigned short*)(scr + 144 * MB);  // 64MB
  unsigned short* w2T   = (unsigned short*)(scr + 208 * MB);  // 64MB
  unsigned short* p2    = (unsigned short*)(scr + 280 * MB);  // 32MB split-K bf16 partials
  unsigned short* hb    = (unsigned short*)d_ws;              // 8MB
  unsigned short* wlmT  = (unsigned short*)((char*)d_ws + 8 * MB); // 65.5MB
  const size_t EE = (size_t)E_ * E_;
  bool lm_fast = ws_size >= 8 * MB + (size_t)V_ * E_ * 2 + 1024;

  k_embed<<<M_, 256, 0, stream>>>(idx, tok, pos, xf);

  k_wt<<<dim3(16, 16, L_), 256, 0, stream>>>(Wq, wqkvT,          E_, E_, EE, 3 * EE);
  k_wt<<<dim3(16, 16, L_), 256, 0, stream>>>(Wk, wqkvT + EE,     E_, E_, EE, 3 * EE);
  k_wt<<<dim3(16, 16, L_), 256, 0, stream>>>(Wv, wqkvT + 2 * EE, E_, E_, EE, 3 * EE);
  k_wt<<<dim3(16, 16, L_), 256, 0, stream>>>(Wo, woT,            E_, E_, EE, EE);
  k_wt<<<dim3(64, 16, L_), 256, 0, stream>>>(W1, w1T, E_, 4 * E_, 4 * EE, 4 * EE);
  k_wt<<<dim3(16, 64, L_), 256, 0, stream>>>(W2, w2T, 4 * E_, E_, 4 * EE, 4 * EE);
  if (lm_fast)
    k_wt<<<dim3(V_ / 64, 16, 1), 256, 0, stream>>>(Wlm, wlmT, E_, V_, 0, 0);

  // ln1 of layer 0; subsequent LNs fused into k_red4ln
  k_ln_bf<<<M_, 256, 0, stream>>>(xf, ln1g, ln1b, hb);

  for (int l = 0; l < L_; ++l) {
    // QKV: 256x192 tile -> 16x16 = 256 blocks (full CU utilization)
    k_gemm_256<1, false, 0, 3><<<16 * (QKVS_ / 192), 512, 0, stream>>>(
        hb, wqkvT + (size_t)l * 3 * EE, nullptr, qkvb, QKVS_, E_, E_);
    k_fattn<<<dim3(T_ / 128, B_ * H_), 256, 0, stream>>>(qkvb, ob);
    // Wo: split-K=4 -> bf16 partials -> fused reduce(+bo+residual) + ln2 -> hb
    k_gemm_256<1, false, 2, 4><<<256, 512, 0, stream>>>(
        ob, woT + (size_t)l * EE, nullptr, p2, E_, E_ / 4, E_);
    k_red4ln<<<M_, 256, 0, stream>>>(p2, bo + l * E_, xf, ln2g + l * E_, ln2b + l * E_, hb);
    k_gemm_256<1, true, 0, 4><<<16 * (4 * E_ / 256), 512, 0, stream>>>(
        hb, w1T + (size_t)l * 4 * EE, b1 + (size_t)l * 4 * E_, mh, 4 * E_, E_, E_);
    // MLP2: split-K=4 -> bf16 partials -> fused reduce(+b2+residual) + next-layer LN
    k_gemm_256<1, false, 2, 4><<<256, 512, 0, stream>>>(
        mh, w2T + (size_t)l * 4 * EE, nullptr, p2, E_, E_, 4 * E_);
    const float* ng = (l + 1 < L_) ? (ln1g + (size_t)(l + 1) * E_) : lnfg;
    const float* nb = (l + 1 < L_) ? (ln1b + (size_t)(l + 1) * E_) : lnfb;
    k_red4ln<<<M_, 256, 0, stream>>>(p2, b2 + l * E_, xf, ng, nb, hb);
  }
  // hb now holds lnf(x)
  if (lm_fast)
    k_gemm_256<0, false, 1, 4><<<16 * (V_ / 256), 512, 0, stream>>>(
        hb, wlmT, blm, (float*)d_out, V_, E_, E_);
  else
    k_gemm_bf<0, false, false><<<dim3(32, V_ / 128), 256, 0, stream>>>(
        hb, Wlm, blm, nullptr, (float*)d_out, M_, V_, E_);
}

// Round 15
// 2400.058 us; speedup vs baseline: 1.0359x; 1.0359x over previous
//
#include <hip/hip_runtime.h>
#include <math.h>

#define L_ 8
#define H_ 16
#define E_ 1024
#define V_ 32000
#define B_ 4
#define T_ 1024
#define HS_ 64
#define M_ 4096   // B*T
#define QKVS_ 3072  // fused qkv row stride

typedef __attribute__((ext_vector_type(8))) short short8;
typedef __attribute__((ext_vector_type(4))) float f32x4;

__device__ __forceinline__ unsigned short f2bf(float f) {
  unsigned int u = __builtin_bit_cast(unsigned int, f);
  u += 0x7fffu + ((u >> 16) & 1u);          // RNE
  return (unsigned short)(u >> 16);
}
__device__ __forceinline__ float bf2f(unsigned short u) {
  unsigned int v = ((unsigned int)u) << 16;
  return __builtin_bit_cast(float, v);
}

// ---------------------------------------------------------------- embed (fp32 x)
__global__ __launch_bounds__(256) void k_embed(
    const int* __restrict__ idx, const float* __restrict__ tok,
    const float* __restrict__ pos, float* __restrict__ x) {
  int bt = blockIdx.x;
  int t  = bt & (T_ - 1);
  int token = idx[bt];
  const float4* te = (const float4*)(tok + (size_t)token * E_);
  const float4* pe = (const float4*)(pos + (size_t)t * E_);
  float4* xo = (float4*)(x + (size_t)bt * E_);
  int i = threadIdx.x;
  float4 a = te[i], b = pe[i];
  xo[i] = make_float4(a.x + b.x, a.y + b.y, a.z + b.z, a.w + b.w);
}

// ---------------------------------------------------------------- weight transpose+convert (vectorized)
__global__ __launch_bounds__(256) void k_wt(
    const float* __restrict__ W, unsigned short* __restrict__ WT,
    int K, int N, size_t ss, size_t ds) {
  __shared__ unsigned short t[64][68];
  const float* Ws = W + (size_t)blockIdx.z * ss;
  unsigned short* Wd = WT + (size_t)blockIdx.z * ds;
  int n0 = blockIdx.x * 64, k0 = blockIdx.y * 64;
  int tid = threadIdx.x;
  int c4 = (tid & 15) * 4, r16 = tid >> 4;
  #pragma unroll
  for (int i = 0; i < 4; ++i) {
    int kr = i * 16 + r16;
    float4 v = *(const float4*)&Ws[(size_t)(k0 + kr) * N + n0 + c4];
    ushort4 pk;
    pk.x = f2bf(v.x); pk.y = f2bf(v.y); pk.z = f2bf(v.z); pk.w = f2bf(v.w);
    *(ushort4*)&t[kr][c4] = pk;
  }
  __syncthreads();
  #pragma unroll
  for (int i = 0; i < 4; ++i) {
    int nr = i * 16 + r16;
    ushort4 o;
    o.x = t[c4 + 0][nr]; o.y = t[c4 + 1][nr];
    o.z = t[c4 + 2][nr]; o.w = t[c4 + 3][nr];
    *(ushort4*)&Wd[(size_t)(n0 + nr) * K + k0 + c4] = o;
  }
}

// ---------------------------------------------------------------- layernorm (fp32 in, bf16 out)
__device__ __forceinline__ float blk_sum256(float v, float* red) {
  #pragma unroll
  for (int o = 1; o < 64; o <<= 1) v += __shfl_xor(v, o);
  int wid = threadIdx.x >> 6, lane = threadIdx.x & 63;
  if (lane == 0) red[wid] = v;
  __syncthreads();
  v = red[0] + red[1] + red[2] + red[3];
  __syncthreads();
  return v;
}

__global__ __launch_bounds__(256) void k_ln_bf(
    const float* __restrict__ X, const float* __restrict__ g,
    const float* __restrict__ b, unsigned short* __restrict__ Y) {
  __shared__ float red[4];
  int row = blockIdx.x;
  int i = threadIdx.x;
  float4 xv = ((const float4*)(X + (size_t)row * E_))[i];
  float s = xv.x + xv.y + xv.z + xv.w;
  s = blk_sum256(s, red);
  float mean = s * (1.0f / E_);
  float dx = xv.x - mean, dy = xv.y - mean, dz = xv.z - mean, dw = xv.w - mean;
  float vs = dx*dx + dy*dy + dz*dz + dw*dw;
  vs = blk_sum256(vs, red);
  float rstd = rsqrtf(vs * (1.0f / E_) + 1e-5f);
  float4 gv = ((const float4*)g)[i];
  float4 bv = ((const float4*)b)[i];
  ushort4 o;
  o.x = f2bf(dx * rstd * gv.x + bv.x);
  o.y = f2bf(dy * rstd * gv.y + bv.y);
  o.z = f2bf(dz * rstd * gv.z + bv.z);
  o.w = f2bf(dw * rstd * gv.w + bv.w);
  ((ushort4*)(Y + (size_t)row * E_))[i] = o;
}

// ---------------------------------------------------------------- fused split-K reduce + residual + next-LN
__global__ __launch_bounds__(256) void k_red4ln(
    const unsigned short* __restrict__ p, const float* __restrict__ bias,
    float* __restrict__ xf, const float* __restrict__ g,
    const float* __restrict__ b, unsigned short* __restrict__ hb) {
  __shared__ float red[4];
  const int ME = M_ * E_;
  int row = blockIdx.x;
  int tid = threadIdx.x;
  int i = row * E_ + tid * 4;
  ushort4 a  = *(const ushort4*)(p + i);
  ushort4 b2 = *(const ushort4*)(p + ME + i);
  ushort4 c  = *(const ushort4*)(p + 2 * ME + i);
  ushort4 d  = *(const ushort4*)(p + 3 * ME + i);
  float4 bv = *(const float4*)(bias + tid * 4);
  float4 x  = *(float4*)(xf + i);
  x.x += bf2f(a.x) + bf2f(b2.x) + bf2f(c.x) + bf2f(d.x) + bv.x;
  x.y += bf2f(a.y) + bf2f(b2.y) + bf2f(c.y) + bf2f(d.y) + bv.y;
  x.z += bf2f(a.z) + bf2f(b2.z) + bf2f(c.z) + bf2f(d.z) + bv.z;
  x.w += bf2f(a.w) + bf2f(b2.w) + bf2f(c.w) + bf2f(d.w) + bv.w;
  *(float4*)(xf + i) = x;
  float s = x.x + x.y + x.z + x.w;
  s = blk_sum256(s, red);
  float mean = s * (1.0f / E_);
  float dx = x.x - mean, dy = x.y - mean, dz = x.z - mean, dw = x.w - mean;
  float vs = dx*dx + dy*dy + dz*dz + dw*dw;
  vs = blk_sum256(vs, red);
  float rstd = rsqrtf(vs * (1.0f / E_) + 1e-5f);
  float4 gv = ((const float4*)g)[tid];
  float4 lb = ((const float4*)b)[tid];
  ushort4 o;
  o.x = f2bf(dx * rstd * gv.x + lb.x);
  o.y = f2bf(dy * rstd * gv.y + lb.y);
  o.z = f2bf(dz * rstd * gv.z + lb.z);
  o.w = f2bf(dw * rstd * gv.w + lb.w);
  ((ushort4*)(hb + (size_t)row * E_))[tid] = o;
}

#define GLDS(src, dst) __builtin_amdgcn_global_load_lds( \
    (const __attribute__((address_space(1))) void*)(src), \
    (__attribute__((address_space(3))) void*)(dst), 16, 0, 0)

#define BAR() do { asm volatile("" ::: "memory"); __builtin_amdgcn_s_barrier(); \
                   asm volatile("" ::: "memory"); } while (0)

// ---------------------------------------------------------------- 256xBN 8-phase bf16 GEMM (BK=64)
// DEC: 0 = m-fastest, 1 = LM head (msub8-fastest), 2 = split-K=4 partials.
template<int OT, bool RELU, int DEC, int NF>
__global__ __launch_bounds__(512, 2) void k_gemm_256(
    const unsigned short* __restrict__ A, const unsigned short* __restrict__ BT,
    const float* __restrict__ bias, void* __restrict__ Cout, int N, int K, int Kstr) {
  constexpr int BUFA = 16384;        // 256*64
  constexpr int BUFB = NF * 4096;    // BN*64
  constexpr int BN = NF * 64;
  __shared__ __attribute__((aligned(16))) unsigned short As[2 * BUFA];
  __shared__ __attribute__((aligned(16))) unsigned short Bs[2 * BUFB];
  int tid = threadIdx.x;
  int lane = tid & 63, w = tid >> 6;           // 8 waves
  int lr = lane & 15, lq = (lane >> 4) & 3;
  int wm = w >> 2, wn = w & 3;                 // 2 x 4 wave grid

  // bijective XCD swizzle (m204)
  int nwg = gridDim.x, orig = blockIdx.x;
  int qq = nwg >> 3, rr = nwg & 7;
  int xcd = orig & 7, lid = orig >> 3;
  int wg = (xcd < rr ? xcd * (qq + 1) : rr * (qq + 1) + (xcd - rr) * qq) + lid;
  int m0, n0, kofs = 0;
  size_t cofs = 0;
  if constexpr (DEC == 0) { m0 = (wg & 15) * 256; n0 = (wg >> 4) * BN; }
  else if constexpr (DEC == 1) {
    int nbn = N / BN;
    int msub = wg & 7;
    int rest = wg >> 3;
    int nb = rest % nbn;
    int msup = rest / nbn;
    m0 = (msup * 8 + msub) * 256;
    n0 = nb * BN;
  } else {
    int inner = wg & 63;
    m0 = (inner & 15) * 256; n0 = (inner >> 4) * BN;
    int ks = wg >> 6;
    kofs = ks * K;
    cofs = (size_t)ks * M_ * (size_t)N;
  }

  // staging: chunk swizzle c8_src = (lane&7) ^ (lane>>3); dest linear
  int srow = w * 8 + (lane >> 3);
  int skoff = ((lane & 7) ^ (lane >> 3)) * 8;
  const unsigned short* aS = A + (size_t)(m0 + srow) * Kstr + kofs + skoff;
  const unsigned short* bS = BT + (size_t)(n0 + srow) * Kstr + kofs + skoff;

#define STG_A1(bo, g, tt) GLDS(aS + (size_t)((g) * 64) * Kstr + (tt) * 64, \
                               &As[(bo) + (((g) * 64) << 6) + (w << 9)])
#define STG_B1(bo, g, tt) GLDS(bS + (size_t)((g) * 64) * Kstr + (tt) * 64, \
                               &Bs[(bo) + (((g) * 64) << 6) + (w << 9)])
#define LDA_(dst, mh, ks) { _Pragma("unroll") for (int m_ = 0; m_ < 4; ++m_) \
  dst[m_] = *(const short8*)&As[soA + ((wm * 128 + (mh) * 64 + m_ * 16 + lr) << 6) + ((((ks) * 4 + lq) ^ (lr & 7)) << 3)]; }
#define LDB_(dst, ks) { _Pragma("unroll") for (int n_ = 0; n_ < NF; ++n_) \
  dst[n_] = *(const short8*)&Bs[soB + ((wn * (16 * NF) + n_ * 16 + lr) << 6) + ((((ks) * 4 + lq) ^ (lr & 7)) << 3)]; }
#define MMA(afr, mofs) do { __builtin_amdgcn_s_setprio(1); \
  _Pragma("unroll") for (int m_ = 0; m_ < 4; ++m_) { \
    _Pragma("unroll") for (int n_ = 0; n_ < NF; ++n_) \
      acc[(mofs) + m_][n_] = __builtin_amdgcn_mfma_f32_16x16x32_bf16(afr[m_], bfr[n_], acc[(mofs) + m_][n_], 0, 0, 0); } \
  __builtin_amdgcn_s_setprio(0); } while (0)

  f32x4 acc[8][NF] = {};
  const int NT = K >> 6;

  // prologue: tile0 full (4+NF loads) + B(t1) g0,g1 -> vmcnt(2)
  #pragma unroll
  for (int g = 0; g < 4; ++g) STG_A1(0, g, 0);
  #pragma unroll
  for (int g = 0; g < NF; ++g) STG_B1(0, g, 0);
  if (NT > 1) {
    STG_B1(BUFB, 0, 1); STG_B1(BUFB, 1, 1);
    asm volatile("s_waitcnt vmcnt(2)" ::: "memory");
  } else {
    asm volatile("s_waitcnt vmcnt(0)" ::: "memory");
  }
  BAR();

  for (int t = 0; t < NT; ++t) {
    const int soA = (t & 1) * BUFA, soB = (t & 1) * BUFB;
    const int nbA = ((t + 1) & 1) * BUFA, nbB = ((t + 1) & 1) * BUFB;
    short8 af0[4], af1[4], bfr[NF];
    // ---- P0: stage B-hi(t+1) -> idle
    LDA_(af0, 0, 0);
    LDB_(bfr, 0);
    if (t + 1 < NT) {
      STG_B1(nbB, 2, t + 1);
      if constexpr (NF == 4) STG_B1(nbB, 3, t + 1);
    }
    BAR(); MMA(af0, 0); BAR();
    // ---- P1: stage A-lo(t+1) -> idle
    LDA_(af1, 1, 0);
    if (t + 1 < NT) { STG_A1(nbA, 0, t + 1); STG_A1(nbA, 1, t + 1); }
    BAR(); MMA(af1, 4); BAR();
    // ---- P2: stage A-hi(t+1) -> idle
    LDA_(af0, 0, 1);
    LDB_(bfr, 1);
    if (t + 1 < NT) { STG_A1(nbA, 2, t + 1); STG_A1(nbA, 3, t + 1); }
    BAR(); MMA(af0, 0); BAR();
    // ---- P3: stage B-lo(t+2) -> current buffer B region (dead after P2)
    LDA_(af1, 1, 1);
    if (t + 2 < NT) { STG_B1(soB, 0, t + 2); STG_B1(soB, 1, t + 2); }
    BAR(); MMA(af1, 4);
    if (t + 2 < NT) { asm volatile("s_waitcnt vmcnt(2)" ::: "memory"); }
    else            { asm volatile("s_waitcnt vmcnt(0)" ::: "memory"); }
    BAR();
  }

  #pragma unroll
  for (int m = 0; m < 8; ++m) {
    #pragma unroll
    for (int n = 0; n < NF; ++n) {
      int col = n0 + wn * (16 * NF) + n * 16 + lr;
      float bv = bias ? bias[col] : 0.0f;
      #pragma unroll
      for (int i = 0; i < 4; ++i) {
        size_t row = (size_t)(m0 + wm * 128 + m * 16 + lq * 4 + i);
        float v = acc[m][n][i] + bv;
        if (RELU) v = fmaxf(v, 0.0f);
        if (OT == 0) ((float*)Cout)[cofs + row * N + col] = v;
        else ((unsigned short*)Cout)[cofs + row * N + col] = f2bf(v);
      }
    }
  }
#undef STG_A1
#undef STG_B1
#undef LDA_
#undef LDB_
#undef MMA
}

// ---------------------------------------------------------------- bf16 TN MFMA GEMM (2-phase, BN<=128)
template<int BN, int OT, bool RELU, bool RES>
__global__ __launch_bounds__(256) void k_gemm_tn(
    const unsigned short* __restrict__ A, const unsigned short* __restrict__ BT,
    const float* __restrict__ bias, const float* __restrict__ R,
    void* __restrict__ Cout, int M, int N, int K) {
  constexpr int NF = BN / 32;
  __shared__ __attribute__((aligned(16))) unsigned short As[128 * 64];
  __shared__ __attribute__((aligned(16))) unsigned short Bs[BN * 64];
  int tid = threadIdx.x;
  int lane = tid & 63, w = tid >> 6;
  int lr = lane & 15, lq = lane >> 4;
  int m0 = blockIdx.x * 128, n0 = blockIdx.y * BN;
  int wr = (w >> 1) * 64, wc = (w & 1) * (BN / 2);

  int srow = w * 8 + (lane >> 3);
  int skoff = ((lane & 7) ^ (lane >> 3)) * 8;
  const unsigned short* a0 = A + (size_t)(m0 + srow) * K + skoff;
  const unsigned short* b0 = BT + (size_t)(n0 + srow) * K + skoff;

  f32x4 acc[4][NF] = {};

  for (int k0 = 0; k0 < K; k0 += 64) {
    __syncthreads();
    #pragma unroll
    for (int j = 0; j < 4; ++j)
      __builtin_amdgcn_global_load_lds(
          (const __attribute__((address_space(1))) void*)(a0 + (size_t)(j * 32) * K + k0),
          (__attribute__((address_space(3))) void*)(As + j * 2048 + w * 512), 16, 0, 0);
    #pragma unroll
    for (int j = 0; j < NF; ++j)
      __builtin_amdgcn_global_load_lds(
          (const __attribute__((address_space(1))) void*)(b0 + (size_t)(j * 32) * K + k0),
          (__attribute__((address_space(3))) void*)(Bs + j * 2048 + w * 512), 16, 0, 0);
    __syncthreads();
    short8 af[4][2], bf[NF][2];
    #pragma unroll
    for (int m = 0; m < 4; ++m)
      #pragma unroll
      for (int ks = 0; ks < 2; ++ks)
        af[m][ks] = *(const short8*)&As[(wr + m * 16 + lr) * 64 + (((ks * 4 + lq) ^ (lr & 7)) << 3)];
    #pragma unroll
    for (int n = 0; n < NF; ++n)
      #pragma unroll
      for (int ks = 0; ks < 2; ++ks)
        bf[n][ks] = *(const short8*)&Bs[(wc + n * 16 + lr) * 64 + (((ks * 4 + lq) ^ (lr & 7)) << 3)];
    #pragma unroll
    for (int ks = 0; ks < 2; ++ks)
      #pragma unroll
      for (int m = 0; m < 4; ++m)
        #pragma unroll
        for (int n = 0; n < NF; ++n)
          acc[m][n] = __builtin_amdgcn_mfma_f32_16x16x32_bf16(af[m][ks], bf[n][ks], acc[m][n], 0, 0, 0);
  }

  #pragma unroll
  for (int m = 0; m < 4; ++m) {
    #pragma unroll
    for (int n = 0; n < NF; ++n) {
      int col = n0 + wc + n * 16 + lr;
      float bv = bias ? bias[col] : 0.0f;
      #pragma unroll
      for (int i = 0; i < 4; ++i) {
        size_t row = (size_t)(m0 + wr + m * 16 + lq * 4 + i);
        float v = acc[m][n][i] + bv;
        if (RELU) v = fmaxf(v, 0.0f);
        if (RES)  v += R[row * N + col];
        if (OT == 0) ((float*)Cout)[row * N + col] = v;
        else ((unsigned short*)Cout)[row * N + col] = f2bf(v);
      }
    }
  }
}

// ---------------------------------------------------------------- legacy GEMM (fp32 B) for LM fallback
template<int OT, bool RELU, bool RES>
__global__ __launch_bounds__(256) void k_gemm_bf(
    const unsigned short* __restrict__ A, const float* __restrict__ W,
    const float* __restrict__ bias, const float* __restrict__ R,
    void* __restrict__ Cout, int M, int N, int K) {
  __shared__ unsigned short As[128][40];
  __shared__ unsigned short Bs[128][40];
  int tid = threadIdx.x;
  int lane = tid & 63, wid = tid >> 6;
  int m0 = blockIdx.x * 128, n0 = blockIdx.y * 128;
  int wr = (wid >> 1) * 64, wc = (wid & 1) * 64;
  f32x4 acc[4][4] = {};
  int a_row = tid >> 1, a_koff = (tid & 1) * 16;
  int b_nb = tid & 31, b_kb = (tid >> 5) * 4;
  int lr = lane & 15, lq = lane >> 4;
  for (int k0 = 0; k0 < K; k0 += 32) {
    const unsigned short* ap = A + (size_t)(m0 + a_row) * K + k0 + a_koff;
    uint4 av0 = *(const uint4*)ap;
    uint4 av1 = *(const uint4*)(ap + 8);
    float wv[4][4];
    #pragma unroll
    for (int dk = 0; dk < 4; ++dk) {
      const float* wrow = W + (size_t)(k0 + b_kb + dk) * N + n0 + b_nb;
      #pragma unroll
      for (int j = 0; j < 4; ++j) wv[j][dk] = wrow[32 * j];
    }
    __syncthreads();
    *(uint4*)&As[a_row][a_koff]     = av0;
    *(uint4*)&As[a_row][a_koff + 8] = av1;
    #pragma unroll
    for (int j = 0; j < 4; ++j) {
      ushort4 pk;
      pk.x = f2bf(wv[j][0]); pk.y = f2bf(wv[j][1]);
      pk.z = f2bf(wv[j][2]); pk.w = f2bf(wv[j][3]);
      *(ushort4*)&Bs[b_nb + 32 * j][b_kb] = pk;
    }
    __syncthreads();
    short8 af[4], bf[4];
    #pragma unroll
    for (int m = 0; m < 4; ++m) af[m] = *(const short8*)&As[wr + m * 16 + lr][lq * 8];
    #pragma unroll
    for (int n = 0; n < 4; ++n) bf[n] = *(const short8*)&Bs[wc + n * 16 + lr][lq * 8];
    #pragma unroll
    for (int m = 0; m < 4; ++m)
      #pragma unroll
      for (int n = 0; n < 4; ++n)
        acc[m][n] = __builtin_amdgcn_mfma_f32_16x16x32_bf16(af[m], bf[n], acc[m][n], 0, 0, 0);
  }
  #pragma unroll
  for (int m = 0; m < 4; ++m) {
    #pragma unroll
    for (int n = 0; n < 4; ++n) {
      int col = n0 + wc + n * 16 + lr;
      float bv = bias ? bias[col] : 0.0f;
      #pragma unroll
      for (int i = 0; i < 4; ++i) {
        size_t row = (size_t)(m0 + wr + m * 16 + lq * 4 + i);
        float v = acc[m][n][i] + bv;
        if (RELU) v = fmaxf(v, 0.0f);
        if (RES)  v += R[row * N + col];
        if (OT == 0) ((float*)Cout)[row * N + col] = v;
        else ((unsigned short*)Cout)[row * N + col] = f2bf(v);
      }
    }
  }
}

// ---------------------------------------------------------------- flash attention (bf16 MFMA, KVBLK=128)
// 4 waves x 32 q-rows = 128-row Q tile; KV tiles of 128 keys (halves barriers/shfl per key).
__global__ __launch_bounds__(256) void k_fattn(
    const unsigned short* __restrict__ QKV, unsigned short* __restrict__ O) {
  __shared__ unsigned short Ks[128][72];     // [k][d] 144B rows
  __shared__ unsigned short Vs[64][136];     // [d][k] transposed, 272B rows (16B aligned)
  __shared__ unsigned short Pl[4][32][136];  // per-wave P transpose
  int tid = threadIdx.x;
  int lane = tid & 63, wid = tid >> 6;
  int lr = lane & 15, lq = lane >> 4;
  int qt = blockIdx.x, bh = blockIdx.y;
  int b = bh >> 4, h = bh & 15;
  size_t base = ((size_t)b * T_) * QKVS_ + h * HS_;
  int q0w = qt * 128 + wid * 32;

  short8 qf[2][2];
  #pragma unroll
  for (int g = 0; g < 2; ++g)
    #pragma unroll
    for (int s = 0; s < 2; ++s)
      qf[g][s] = *(const short8*)(QKV + base + (size_t)(q0w + g * 16 + lr) * QKVS_ + s * 32 + lq * 8);

  f32x4 o_acc[2][4] = {};
  float mrun[2][4], lrun[2][4];
  #pragma unroll
  for (int g = 0; g < 2; ++g)
    #pragma unroll
    for (int i = 0; i < 4; ++i) { mrun[g][i] = -1e30f; lrun[g][i] = 0.0f; }
  const float sc = 0.03125f * 1.44269504f;
  int r = tid >> 2, cc = (tid & 3) * 16;     // key r & r+64, d-chunk cc
  int ntiles = qt + 1;

  uint4 kA0, kA1, kB0, kB1, vA0, vA1, vB0, vB1;
  {
    const unsigned short* kp = QKV + base + 1024 + (size_t)r * QKVS_ + cc;
    kA0 = *(const uint4*)kp; kA1 = *(const uint4*)(kp + 8);
    vA0 = *(const uint4*)(kp + 1024); vA1 = *(const uint4*)(kp + 1032);
    const unsigned short* kp2 = kp + (size_t)64 * QKVS_;
    kB0 = *(const uint4*)kp2; kB1 = *(const uint4*)(kp2 + 8);
    vB0 = *(const uint4*)(kp2 + 1024); vB1 = *(const uint4*)(kp2 + 1032);
  }

  for (int t = 0; t < ntiles; ++t) {
    __syncthreads();                         // prev tile's LDS reads done
    *(uint4*)&Ks[r][cc] = kA0;
    *(uint4*)&Ks[r][cc + 8] = kA1;
    *(uint4*)&Ks[64 + r][cc] = kB0;
    *(uint4*)&Ks[64 + r][cc + 8] = kB1;
    unsigned short vt[16];
    *(uint4*)&vt[0] = vA0; *(uint4*)&vt[8] = vA1;
    #pragma unroll
    for (int j = 0; j < 16; ++j) Vs[cc + j][r] = vt[j];
    *(uint4*)&vt[0] = vB0; *(uint4*)&vt[8] = vB1;
    #pragma unroll
    for (int j = 0; j < 16; ++j) Vs[cc + j][64 + r] = vt[j];
    __syncthreads();                         // staging visible
    if (t + 1 < ntiles) {                    // T14: hide next-tile HBM under compute
      const unsigned short* kp = QKV + base + 1024 + (size_t)((t + 1) * 128 + r) * QKVS_ + cc;
      kA0 = *(const uint4*)kp; kA1 = *(const uint4*)(kp + 8);
      vA0 = *(const uint4*)(kp + 1024); vA1 = *(const uint4*)(kp + 1032);
      const unsigned short* kp2 = kp + (size_t)64 * QKVS_;
      kB0 = *(const uint4*)kp2; kB1 = *(const uint4*)(kp2 + 8);
      vB0 = *(const uint4*)(kp2 + 1024); vB1 = *(const uint4*)(kp2 + 1032);
    }

    bool diag = (t == qt);
    float p[2][8][4];
    #pragma unroll
    for (int nt = 0; nt < 8; ++nt) {
      f32x4 s0 = {}, s1 = {};
      #pragma unroll
      for (int s = 0; s < 2; ++s) {
        short8 kf = *(const short8*)&Ks[nt * 16 + lr][s * 32 + lq * 8];
        s0 = __builtin_amdgcn_mfma_f32_16x16x32_bf16(qf[0][s], kf, s0, 0, 0, 0);
        s1 = __builtin_amdgcn_mfma_f32_16x16x32_bf16(qf[1][s], kf, s1, 0, 0, 0);
      }
      #pragma unroll
      for (int i = 0; i < 4; ++i) {
        float v0 = s0[i] * sc, v1 = s1[i] * sc;
        if (diag) {
          int col = t * 128 + nt * 16 + lr;
          if (col > q0w + lq * 4 + i) v0 = -1e30f;
          if (col > q0w + 16 + lq * 4 + i) v1 = -1e30f;
        }
        p[0][nt][i] = v0;
        p[1][nt][i] = v1;
      }
    }
    #pragma unroll
    for (int g = 0; g < 2; ++g)
      #pragma unroll
      for (int i = 0; i < 4; ++i) {
        float v = fmaxf(fmaxf(fmaxf(p[g][0][i], p[g][1][i]), fmaxf(p[g][2][i], p[g][3][i])),
                        fmaxf(fmaxf(p[g][4][i], p[g][5][i]), fmaxf(p[g][6][i], p[g][7][i])));
        #pragma unroll
        for (int o = 1; o < 16; o <<= 1) v = fmaxf(v, __shfl_xor(v, o));
        if (v > mrun[g][i] + 10.0f) {        // T13 defer-max
          float corr = __builtin_amdgcn_exp2f(mrun[g][i] - v);
          mrun[g][i] = v;
          lrun[g][i] *= corr;
          #pragma unroll
          for (int dn = 0; dn < 4; ++dn) o_acc[g][dn][i] *= corr;
        }
        float mn = mrun[g][i];
        float ps = 0.0f;
        #pragma unroll
        for (int nt = 0; nt < 8; ++nt) {
          float pe = __builtin_amdgcn_exp2f(p[g][nt][i] - mn);
          p[g][nt][i] = pe;
          ps += pe;
        }
        lrun[g][i] += ps;
      }
    // P -> per-wave LDS transpose; intra-wave DS ordering suffices (no barrier)
    #pragma unroll
    for (int g = 0; g < 2; ++g)
      #pragma unroll
      for (int nt = 0; nt < 8; ++nt)
        #pragma unroll
        for (int i = 0; i < 4; ++i)
          Pl[wid][g * 16 + lq * 4 + i][nt * 16 + lr] = f2bf(p[g][nt][i]);

    #pragma unroll
    for (int s = 0; s < 4; ++s) {
      short8 pa0 = *(const short8*)&Pl[wid][lr][s * 32 + lq * 8];
      short8 pa1 = *(const short8*)&Pl[wid][16 + lr][s * 32 + lq * 8];
      #pragma unroll
      for (int dn = 0; dn < 4; ++dn) {
        short8 vf = *(const short8*)&Vs[dn * 16 + lr][s * 32 + lq * 8];
        o_acc[0][dn] = __builtin_amdgcn_mfma_f32_16x16x32_bf16(pa0, vf, o_acc[0][dn], 0, 0, 0);
        o_acc[1][dn] = __builtin_amdgcn_mfma_f32_16x16x32_bf16(pa1, vf, o_acc[1][dn], 0, 0, 0);
      }
    }
  }

  #pragma unroll
  for (int g = 0; g < 2; ++g)
    #pragma unroll
    for (int i = 0; i < 4; ++i) {
      float v = lrun[g][i];
      #pragma unroll
      for (int o = 1; o < 16; o <<= 1) v += __shfl_xor(v, o);
      lrun[g][i] = 1.0f / v;
    }
  #pragma unroll
  for (int g = 0; g < 2; ++g)
    #pragma unroll
    for (int dn = 0; dn < 4; ++dn)
      #pragma unroll
      for (int i = 0; i < 4; ++i) {
        size_t row = (size_t)(b * T_) + q0w + g * 16 + lq * 4 + i;
        O[row * E_ + h * HS_ + dn * 16 + lr] = f2bf(o_acc[g][dn][i] * lrun[g][i]);
      }
}

// ---------------------------------------------------------------- launch
extern "C" void kernel_launch(void* const* d_in, const int* in_sizes, int n_in,
                              void* d_out, int out_size, void* d_ws, size_t ws_size,
                              hipStream_t stream) {
  const int*   idx  = (const int*)d_in[0];
  const float* tok  = (const float*)d_in[1];
  const float* pos  = (const float*)d_in[2];
  const float* ln1g = (const float*)d_in[3];
  const float* ln1b = (const float*)d_in[4];
  const float* Wq   = (const float*)d_in[5];
  const float* Wk   = (const float*)d_in[6];
  const float* Wv   = (const float*)d_in[7];
  const float* Wo   = (const float*)d_in[8];
  const float* bo   = (const float*)d_in[9];
  const float* ln2g = (const float*)d_in[10];
  const float* ln2b = (const float*)d_in[11];
  const float* W1   = (const float*)d_in[12];
  const float* b1   = (const float*)d_in[13];
  const float* W2   = (const float*)d_in[14];
  const float* b2   = (const float*)d_in[15];
  const float* lnfg = (const float*)d_in[16];
  const float* lnfb = (const float*)d_in[17];
  const float* Wlm  = (const float*)d_in[18];
  const float* blm  = (const float*)d_in[19];

  char* scr = (char*)d_out;
  const size_t MB = 1024 * 1024;
  float*          xf    = (float*)(scr);                      // 16MB
  unsigned short* qkvb  = (unsigned short*)(scr + 16 * MB);   // 24MB
  unsigned short* ob    = (unsigned short*)(scr + 40 * MB);   // 8MB
  unsigned short* mh    = (unsigned short*)(scr + 48 * MB);   // 32MB
  unsigned short* wqkvT = (unsigned short*)(scr + 80 * MB);   // 48MB
  unsigned short* woT   = (unsigned short*)(scr + 128 * MB);  // 16MB
  unsigned short* w1T   = (unsigned short*)(scr + 144 * MB);  // 64MB
  unsigned short* w2T   = (unsigned short*)(scr + 208 * MB);  // 64MB
  unsigned short* p2    = (unsigned short*)(scr + 280 * MB);  // 32MB split-K bf16 partials
  unsigned short* hb    = (unsigned short*)d_ws;              // 8MB
  unsigned short* wlmT  = (unsigned short*)((char*)d_ws + 8 * MB); // 65.5MB
  const size_t EE = (size_t)E_ * E_;
  bool lm_fast = ws_size >= 8 * MB + (size_t)V_ * E_ * 2 + 1024;

  k_embed<<<M_, 256, 0, stream>>>(idx, tok, pos, xf);

  k_wt<<<dim3(16, 16, L_), 256, 0, stream>>>(Wq, wqkvT,          E_, E_, EE, 3 * EE);
  k_wt<<<dim3(16, 16, L_), 256, 0, stream>>>(Wk, wqkvT + EE,     E_, E_, EE, 3 * EE);
  k_wt<<<dim3(16, 16, L_), 256, 0, stream>>>(Wv, wqkvT + 2 * EE, E_, E_, EE, 3 * EE);
  k_wt<<<dim3(16, 16, L_), 256, 0, stream>>>(Wo, woT,            E_, E_, EE, EE);
  k_wt<<<dim3(64, 16, L_), 256, 0, stream>>>(W1, w1T, E_, 4 * E_, 4 * EE, 4 * EE);
  k_wt<<<dim3(16, 64, L_), 256, 0, stream>>>(W2, w2T, 4 * E_, E_, 4 * EE, 4 * EE);
  if (lm_fast)
    k_wt<<<dim3(V_ / 64, 16, 1), 256, 0, stream>>>(Wlm, wlmT, E_, V_, 0, 0);

  // ln1 of layer 0; subsequent LNs: ln2 standalone, ln1(l+1)/lnf fused into k_red4ln
  k_ln_bf<<<M_, 256, 0, stream>>>(xf, ln1g, ln1b, hb);

  for (int l = 0; l < L_; ++l) {
    // QKV: 256x192 tile -> 256 blocks (full CU utilization)
    k_gemm_256<1, false, 0, 3><<<16 * (QKVS_ / 192), 512, 0, stream>>>(
        hb, wqkvT + (size_t)l * 3 * EE, nullptr, qkvb, QKVS_, E_, E_);
    k_fattn<<<dim3(T_ / 128, B_ * H_), 256, 0, stream>>>(qkvb, ob);
    k_gemm_tn<64, 0, false, true><<<dim3(32, 16), 256, 0, stream>>>(
        ob, woT + (size_t)l * EE, bo + l * E_, xf, xf, M_, E_, E_);
    k_ln_bf<<<M_, 256, 0, stream>>>(xf, ln2g + l * E_, ln2b + l * E_, hb);
    k_gemm_256<1, true, 0, 4><<<16 * (4 * E_ / 256), 512, 0, stream>>>(
        hb, w1T + (size_t)l * 4 * EE, b1 + (size_t)l * 4 * E_, mh, 4 * E_, E_, E_);
    // MLP2: split-K=4 -> bf16 partials -> fused reduce(+b2+residual) + next-layer LN
    k_gemm_256<1, false, 2, 4><<<256, 512, 0, stream>>>(
        mh, w2T + (size_t)l * 4 * EE, nullptr, p2, E_, E_, 4 * E_);
    const float* ng = (l + 1 < L_) ? (ln1g + (size_t)(l + 1) * E_) : lnfg;
    const float* nb = (l + 1 < L_) ? (ln1b + (size_t)(l + 1) * E_) : lnfb;
    k_red4ln<<<M_, 256, 0, stream>>>(p2, b2 + l * E_, xf, ng, nb, hb);
  }
  // hb now holds lnf(x)
  if (lm_fast)
    k_gemm_256<0, false, 1, 4><<<16 * (V_ / 256), 512, 0, stream>>>(
        hb, wlmT, blm, (float*)d_out, V_, E_, E_);
  else
    k_gemm_bf<0, false, false><<<dim3(32, V_ / 128), 256, 0, stream>>>(
        hb, Wlm, blm, nullptr, (float*)d_out, M_, V_, E_);
}

// Round 16
// 2394.130 us; speedup vs baseline: 1.0384x; 1.0025x over previous
//
#include <hip/hip_runtime.h>
#include <math.h>

#define L_ 8
#define H_ 16
#define E_ 1024
#define V_ 32000
#define B_ 4
#define T_ 1024
#define HS_ 64
#define M_ 4096   // B*T
#define QKVS_ 3072  // fused qkv row stride

typedef __attribute__((ext_vector_type(8))) short short8;
typedef __attribute__((ext_vector_type(4))) float f32x4;

__device__ __forceinline__ unsigned short f2bf(float f) {
  unsigned int u = __builtin_bit_cast(unsigned int, f);
  u += 0x7fffu + ((u >> 16) & 1u);          // RNE
  return (unsigned short)(u >> 16);
}
__device__ __forceinline__ float bf2f(unsigned short u) {
  unsigned int v = ((unsigned int)u) << 16;
  return __builtin_bit_cast(float, v);
}

// ---------------------------------------------------------------- embed (fp32 x)
__global__ __launch_bounds__(256) void k_embed(
    const int* __restrict__ idx, const float* __restrict__ tok,
    const float* __restrict__ pos, float* __restrict__ x) {
  int bt = blockIdx.x;
  int t  = bt & (T_ - 1);
  int token = idx[bt];
  const float4* te = (const float4*)(tok + (size_t)token * E_);
  const float4* pe = (const float4*)(pos + (size_t)t * E_);
  float4* xo = (float4*)(x + (size_t)bt * E_);
  int i = threadIdx.x;
  float4 a = te[i], b = pe[i];
  xo[i] = make_float4(a.x + b.x, a.y + b.y, a.z + b.z, a.w + b.w);
}

// ---------------------------------------------------------------- weight transpose+convert (vectorized)
__global__ __launch_bounds__(256) void k_wt(
    const float* __restrict__ W, unsigned short* __restrict__ WT,
    int K, int N, size_t ss, size_t ds) {
  __shared__ unsigned short t[64][68];
  const float* Ws = W + (size_t)blockIdx.z * ss;
  unsigned short* Wd = WT + (size_t)blockIdx.z * ds;
  int n0 = blockIdx.x * 64, k0 = blockIdx.y * 64;
  int tid = threadIdx.x;
  int c4 = (tid & 15) * 4, r16 = tid >> 4;
  #pragma unroll
  for (int i = 0; i < 4; ++i) {
    int kr = i * 16 + r16;
    float4 v = *(const float4*)&Ws[(size_t)(k0 + kr) * N + n0 + c4];
    ushort4 pk;
    pk.x = f2bf(v.x); pk.y = f2bf(v.y); pk.z = f2bf(v.z); pk.w = f2bf(v.w);
    *(ushort4*)&t[kr][c4] = pk;
  }
  __syncthreads();
  #pragma unroll
  for (int i = 0; i < 4; ++i) {
    int nr = i * 16 + r16;
    ushort4 o;
    o.x = t[c4 + 0][nr]; o.y = t[c4 + 1][nr];
    o.z = t[c4 + 2][nr]; o.w = t[c4 + 3][nr];
    *(ushort4*)&Wd[(size_t)(n0 + nr) * K + k0 + c4] = o;
  }
}

// ---------------------------------------------------------------- layernorm (fp32 in, bf16 out)
__device__ __forceinline__ float blk_sum256(float v, float* red) {
  #pragma unroll
  for (int o = 1; o < 64; o <<= 1) v += __shfl_xor(v, o);
  int wid = threadIdx.x >> 6, lane = threadIdx.x & 63;
  if (lane == 0) red[wid] = v;
  __syncthreads();
  v = red[0] + red[1] + red[2] + red[3];
  __syncthreads();
  return v;
}

__global__ __launch_bounds__(256) void k_ln_bf(
    const float* __restrict__ X, const float* __restrict__ g,
    const float* __restrict__ b, unsigned short* __restrict__ Y) {
  __shared__ float red[4];
  int row = blockIdx.x;
  int i = threadIdx.x;
  float4 xv = ((const float4*)(X + (size_t)row * E_))[i];
  float s = xv.x + xv.y + xv.z + xv.w;
  s = blk_sum256(s, red);
  float mean = s * (1.0f / E_);
  float dx = xv.x - mean, dy = xv.y - mean, dz = xv.z - mean, dw = xv.w - mean;
  float vs = dx*dx + dy*dy + dz*dz + dw*dw;
  vs = blk_sum256(vs, red);
  float rstd = rsqrtf(vs * (1.0f / E_) + 1e-5f);
  float4 gv = ((const float4*)g)[i];
  float4 bv = ((const float4*)b)[i];
  ushort4 o;
  o.x = f2bf(dx * rstd * gv.x + bv.x);
  o.y = f2bf(dy * rstd * gv.y + bv.y);
  o.z = f2bf(dz * rstd * gv.z + bv.z);
  o.w = f2bf(dw * rstd * gv.w + bv.w);
  ((ushort4*)(Y + (size_t)row * E_))[i] = o;
}

// ---------------------------------------------------------------- fused split-K reduce + residual + next-LN
__global__ __launch_bounds__(256) void k_red4ln(
    const unsigned short* __restrict__ p, const float* __restrict__ bias,
    float* __restrict__ xf, const float* __restrict__ g,
    const float* __restrict__ b, unsigned short* __restrict__ hb) {
  __shared__ float red[4];
  const int ME = M_ * E_;
  int row = blockIdx.x;
  int tid = threadIdx.x;
  int i = row * E_ + tid * 4;
  ushort4 a  = *(const ushort4*)(p + i);
  ushort4 b2 = *(const ushort4*)(p + ME + i);
  ushort4 c  = *(const ushort4*)(p + 2 * ME + i);
  ushort4 d  = *(const ushort4*)(p + 3 * ME + i);
  float4 bv = *(const float4*)(bias + tid * 4);
  float4 x  = *(float4*)(xf + i);
  x.x += bf2f(a.x) + bf2f(b2.x) + bf2f(c.x) + bf2f(d.x) + bv.x;
  x.y += bf2f(a.y) + bf2f(b2.y) + bf2f(c.y) + bf2f(d.y) + bv.y;
  x.z += bf2f(a.z) + bf2f(b2.z) + bf2f(c.z) + bf2f(d.z) + bv.z;
  x.w += bf2f(a.w) + bf2f(b2.w) + bf2f(c.w) + bf2f(d.w) + bv.w;
  *(float4*)(xf + i) = x;
  float s = x.x + x.y + x.z + x.w;
  s = blk_sum256(s, red);
  float mean = s * (1.0f / E_);
  float dx = x.x - mean, dy = x.y - mean, dz = x.z - mean, dw = x.w - mean;
  float vs = dx*dx + dy*dy + dz*dz + dw*dw;
  vs = blk_sum256(vs, red);
  float rstd = rsqrtf(vs * (1.0f / E_) + 1e-5f);
  float4 gv = ((const float4*)g)[tid];
  float4 lb = ((const float4*)b)[tid];
  ushort4 o;
  o.x = f2bf(dx * rstd * gv.x + lb.x);
  o.y = f2bf(dy * rstd * gv.y + lb.y);
  o.z = f2bf(dz * rstd * gv.z + lb.z);
  o.w = f2bf(dw * rstd * gv.w + lb.w);
  ((ushort4*)(hb + (size_t)row * E_))[tid] = o;
}

#define GLDS(src, dst) __builtin_amdgcn_global_load_lds( \
    (const __attribute__((address_space(1))) void*)(src), \
    (__attribute__((address_space(3))) void*)(dst), 16, 0, 0)

#define BAR() do { asm volatile("" ::: "memory"); __builtin_amdgcn_s_barrier(); \
                   asm volatile("" ::: "memory"); } while (0)

// ---------------------------------------------------------------- 256xBN 8-phase bf16 GEMM (BK=64)
// DEC: 0 = m-fastest, 1 = LM head (msub8-fastest), 2 = split-K=4 partials.
template<int OT, bool RELU, int DEC, int NF>
__global__ __launch_bounds__(512, 2) void k_gemm_256(
    const unsigned short* __restrict__ A, const unsigned short* __restrict__ BT,
    const float* __restrict__ bias, void* __restrict__ Cout, int N, int K, int Kstr) {
  constexpr int BUFA = 16384;        // 256*64
  constexpr int BUFB = NF * 4096;    // BN*64
  constexpr int BN = NF * 64;
  __shared__ __attribute__((aligned(16))) unsigned short As[2 * BUFA];
  __shared__ __attribute__((aligned(16))) unsigned short Bs[2 * BUFB];
  int tid = threadIdx.x;
  int lane = tid & 63, w = tid >> 6;           // 8 waves
  int lr = lane & 15, lq = (lane >> 4) & 3;
  int wm = w >> 2, wn = w & 3;                 // 2 x 4 wave grid

  // bijective XCD swizzle (m204)
  int nwg = gridDim.x, orig = blockIdx.x;
  int qq = nwg >> 3, rr = nwg & 7;
  int xcd = orig & 7, lid = orig >> 3;
  int wg = (xcd < rr ? xcd * (qq + 1) : rr * (qq + 1) + (xcd - rr) * qq) + lid;
  int m0, n0, kofs = 0;
  size_t cofs = 0;
  if constexpr (DEC == 0) { m0 = (wg & 15) * 256; n0 = (wg >> 4) * BN; }
  else if constexpr (DEC == 1) {
    int nbn = N / BN;
    int msub = wg & 7;
    int rest = wg >> 3;
    int nb = rest % nbn;
    int msup = rest / nbn;
    m0 = (msup * 8 + msub) * 256;
    n0 = nb * BN;
  } else {
    int inner = wg & 63;
    m0 = (inner & 15) * 256; n0 = (inner >> 4) * BN;
    int ks = wg >> 6;
    kofs = ks * K;
    cofs = (size_t)ks * M_ * (size_t)N;
  }

  // staging: chunk swizzle c8_src = (lane&7) ^ (lane>>3); dest linear
  int srow = w * 8 + (lane >> 3);
  int skoff = ((lane & 7) ^ (lane >> 3)) * 8;
  const unsigned short* aS = A + (size_t)(m0 + srow) * Kstr + kofs + skoff;
  const unsigned short* bS = BT + (size_t)(n0 + srow) * Kstr + kofs + skoff;

#define STG_A1(bo, g, tt) GLDS(aS + (size_t)((g) * 64) * Kstr + (tt) * 64, \
                               &As[(bo) + (((g) * 64) << 6) + (w << 9)])
#define STG_B1(bo, g, tt) GLDS(bS + (size_t)((g) * 64) * Kstr + (tt) * 64, \
                               &Bs[(bo) + (((g) * 64) << 6) + (w << 9)])
#define LDA_(dst, mh, ks) { _Pragma("unroll") for (int m_ = 0; m_ < 4; ++m_) \
  dst[m_] = *(const short8*)&As[soA + ((wm * 128 + (mh) * 64 + m_ * 16 + lr) << 6) + ((((ks) * 4 + lq) ^ (lr & 7)) << 3)]; }
#define LDB_(dst, ks) { _Pragma("unroll") for (int n_ = 0; n_ < NF; ++n_) \
  dst[n_] = *(const short8*)&Bs[soB + ((wn * (16 * NF) + n_ * 16 + lr) << 6) + ((((ks) * 4 + lq) ^ (lr & 7)) << 3)]; }
#define MMA(afr, mofs) do { __builtin_amdgcn_s_setprio(1); \
  _Pragma("unroll") for (int m_ = 0; m_ < 4; ++m_) { \
    _Pragma("unroll") for (int n_ = 0; n_ < NF; ++n_) \
      acc[(mofs) + m_][n_] = __builtin_amdgcn_mfma_f32_16x16x32_bf16(afr[m_], bfr[n_], acc[(mofs) + m_][n_], 0, 0, 0); } \
  __builtin_amdgcn_s_setprio(0); } while (0)

  f32x4 acc[8][NF] = {};
  const int NT = K >> 6;

  // prologue: tile0 full (4+NF loads) + B(t1) g0,g1 -> vmcnt(2)
  #pragma unroll
  for (int g = 0; g < 4; ++g) STG_A1(0, g, 0);
  #pragma unroll
  for (int g = 0; g < NF; ++g) STG_B1(0, g, 0);
  if (NT > 1) {
    STG_B1(BUFB, 0, 1); STG_B1(BUFB, 1, 1);
    asm volatile("s_waitcnt vmcnt(2)" ::: "memory");
  } else {
    asm volatile("s_waitcnt vmcnt(0)" ::: "memory");
  }
  BAR();

  for (int t = 0; t < NT; ++t) {
    const int soA = (t & 1) * BUFA, soB = (t & 1) * BUFB;
    const int nbA = ((t + 1) & 1) * BUFA, nbB = ((t + 1) & 1) * BUFB;
    short8 af0[4], af1[4], bfr[NF];
    // ---- P0: stage B-hi(t+1) -> idle
    LDA_(af0, 0, 0);
    LDB_(bfr, 0);
    if (t + 1 < NT) {
      STG_B1(nbB, 2, t + 1);
      if constexpr (NF == 4) STG_B1(nbB, 3, t + 1);
    }
    BAR(); MMA(af0, 0); BAR();
    // ---- P1: stage A-lo(t+1) -> idle
    LDA_(af1, 1, 0);
    if (t + 1 < NT) { STG_A1(nbA, 0, t + 1); STG_A1(nbA, 1, t + 1); }
    BAR(); MMA(af1, 4); BAR();
    // ---- P2: stage A-hi(t+1) -> idle
    LDA_(af0, 0, 1);
    LDB_(bfr, 1);
    if (t + 1 < NT) { STG_A1(nbA, 2, t + 1); STG_A1(nbA, 3, t + 1); }
    BAR(); MMA(af0, 0); BAR();
    // ---- P3: stage B-lo(t+2) -> current buffer B region (dead after P2)
    LDA_(af1, 1, 1);
    if (t + 2 < NT) { STG_B1(soB, 0, t + 2); STG_B1(soB, 1, t + 2); }
    BAR(); MMA(af1, 4);
    if (t + 2 < NT) { asm volatile("s_waitcnt vmcnt(2)" ::: "memory"); }
    else            { asm volatile("s_waitcnt vmcnt(0)" ::: "memory"); }
    BAR();
  }

  #pragma unroll
  for (int m = 0; m < 8; ++m) {
    #pragma unroll
    for (int n = 0; n < NF; ++n) {
      int col = n0 + wn * (16 * NF) + n * 16 + lr;
      float bv = bias ? bias[col] : 0.0f;
      #pragma unroll
      for (int i = 0; i < 4; ++i) {
        size_t row = (size_t)(m0 + wm * 128 + m * 16 + lq * 4 + i);
        float v = acc[m][n][i] + bv;
        if (RELU) v = fmaxf(v, 0.0f);
        if (OT == 0) ((float*)Cout)[cofs + row * N + col] = v;
        else ((unsigned short*)Cout)[cofs + row * N + col] = f2bf(v);
      }
    }
  }
#undef STG_A1
#undef STG_B1
#undef LDA_
#undef LDB_
#undef MMA
}

// ---------------------------------------------------------------- bf16 TN MFMA GEMM (2-phase, BN<=128)
template<int BN, int OT, bool RELU, bool RES>
__global__ __launch_bounds__(256) void k_gemm_tn(
    const unsigned short* __restrict__ A, const unsigned short* __restrict__ BT,
    const float* __restrict__ bias, const float* __restrict__ R,
    void* __restrict__ Cout, int M, int N, int K) {
  constexpr int NF = BN / 32;
  __shared__ __attribute__((aligned(16))) unsigned short As[128 * 64];
  __shared__ __attribute__((aligned(16))) unsigned short Bs[BN * 64];
  int tid = threadIdx.x;
  int lane = tid & 63, w = tid >> 6;
  int lr = lane & 15, lq = lane >> 4;
  int m0 = blockIdx.x * 128, n0 = blockIdx.y * BN;
  int wr = (w >> 1) * 64, wc = (w & 1) * (BN / 2);

  int srow = w * 8 + (lane >> 3);
  int skoff = ((lane & 7) ^ (lane >> 3)) * 8;
  const unsigned short* a0 = A + (size_t)(m0 + srow) * K + skoff;
  const unsigned short* b0 = BT + (size_t)(n0 + srow) * K + skoff;

  f32x4 acc[4][NF] = {};

  for (int k0 = 0; k0 < K; k0 += 64) {
    __syncthreads();
    #pragma unroll
    for (int j = 0; j < 4; ++j)
      __builtin_amdgcn_global_load_lds(
          (const __attribute__((address_space(1))) void*)(a0 + (size_t)(j * 32) * K + k0),
          (__attribute__((address_space(3))) void*)(As + j * 2048 + w * 512), 16, 0, 0);
    #pragma unroll
    for (int j = 0; j < NF; ++j)
      __builtin_amdgcn_global_load_lds(
          (const __attribute__((address_space(1))) void*)(b0 + (size_t)(j * 32) * K + k0),
          (__attribute__((address_space(3))) void*)(Bs + j * 2048 + w * 512), 16, 0, 0);
    __syncthreads();
    short8 af[4][2], bf[NF][2];
    #pragma unroll
    for (int m = 0; m < 4; ++m)
      #pragma unroll
      for (int ks = 0; ks < 2; ++ks)
        af[m][ks] = *(const short8*)&As[(wr + m * 16 + lr) * 64 + (((ks * 4 + lq) ^ (lr & 7)) << 3)];
    #pragma unroll
    for (int n = 0; n < NF; ++n)
      #pragma unroll
      for (int ks = 0; ks < 2; ++ks)
        bf[n][ks] = *(const short8*)&Bs[(wc + n * 16 + lr) * 64 + (((ks * 4 + lq) ^ (lr & 7)) << 3)];
    #pragma unroll
    for (int ks = 0; ks < 2; ++ks)
      #pragma unroll
      for (int m = 0; m < 4; ++m)
        #pragma unroll
        for (int n = 0; n < NF; ++n)
          acc[m][n] = __builtin_amdgcn_mfma_f32_16x16x32_bf16(af[m][ks], bf[n][ks], acc[m][n], 0, 0, 0);
  }

  #pragma unroll
  for (int m = 0; m < 4; ++m) {
    #pragma unroll
    for (int n = 0; n < NF; ++n) {
      int col = n0 + wc + n * 16 + lr;
      float bv = bias ? bias[col] : 0.0f;
      #pragma unroll
      for (int i = 0; i < 4; ++i) {
        size_t row = (size_t)(m0 + wr + m * 16 + lq * 4 + i);
        float v = acc[m][n][i] + bv;
        if (RELU) v = fmaxf(v, 0.0f);
        if (RES)  v += R[row * N + col];
        if (OT == 0) ((float*)Cout)[row * N + col] = v;
        else ((unsigned short*)Cout)[row * N + col] = f2bf(v);
      }
    }
  }
}

// ---------------------------------------------------------------- legacy GEMM (fp32 B) for LM fallback
template<int OT, bool RELU, bool RES>
__global__ __launch_bounds__(256) void k_gemm_bf(
    const unsigned short* __restrict__ A, const float* __restrict__ W,
    const float* __restrict__ bias, const float* __restrict__ R,
    void* __restrict__ Cout, int M, int N, int K) {
  __shared__ unsigned short As[128][40];
  __shared__ unsigned short Bs[128][40];
  int tid = threadIdx.x;
  int lane = tid & 63, wid = tid >> 6;
  int m0 = blockIdx.x * 128, n0 = blockIdx.y * 128;
  int wr = (wid >> 1) * 64, wc = (wid & 1) * 64;
  f32x4 acc[4][4] = {};
  int a_row = tid >> 1, a_koff = (tid & 1) * 16;
  int b_nb = tid & 31, b_kb = (tid >> 5) * 4;
  int lr = lane & 15, lq = lane >> 4;
  for (int k0 = 0; k0 < K; k0 += 32) {
    const unsigned short* ap = A + (size_t)(m0 + a_row) * K + k0 + a_koff;
    uint4 av0 = *(const uint4*)ap;
    uint4 av1 = *(const uint4*)(ap + 8);
    float wv[4][4];
    #pragma unroll
    for (int dk = 0; dk < 4; ++dk) {
      const float* wrow = W + (size_t)(k0 + b_kb + dk) * N + n0 + b_nb;
      #pragma unroll
      for (int j = 0; j < 4; ++j) wv[j][dk] = wrow[32 * j];
    }
    __syncthreads();
    *(uint4*)&As[a_row][a_koff]     = av0;
    *(uint4*)&As[a_row][a_koff + 8] = av1;
    #pragma unroll
    for (int j = 0; j < 4; ++j) {
      ushort4 pk;
      pk.x = f2bf(wv[j][0]); pk.y = f2bf(wv[j][1]);
      pk.z = f2bf(wv[j][2]); pk.w = f2bf(wv[j][3]);
      *(ushort4*)&Bs[b_nb + 32 * j][b_kb] = pk;
    }
    __syncthreads();
    short8 af[4], bf[4];
    #pragma unroll
    for (int m = 0; m < 4; ++m) af[m] = *(const short8*)&As[wr + m * 16 + lr][lq * 8];
    #pragma unroll
    for (int n = 0; n < 4; ++n) bf[n] = *(const short8*)&Bs[wc + n * 16 + lr][lq * 8];
    #pragma unroll
    for (int m = 0; m < 4; ++m)
      #pragma unroll
      for (int n = 0; n < 4; ++n)
        acc[m][n] = __builtin_amdgcn_mfma_f32_16x16x32_bf16(af[m], bf[n], acc[m][n], 0, 0, 0);
  }
  #pragma unroll
  for (int m = 0; m < 4; ++m) {
    #pragma unroll
    for (int n = 0; n < 4; ++n) {
      int col = n0 + wc + n * 16 + lr;
      float bv = bias ? bias[col] : 0.0f;
      #pragma unroll
      for (int i = 0; i < 4; ++i) {
        size_t row = (size_t)(m0 + wr + m * 16 + lq * 4 + i);
        float v = acc[m][n][i] + bv;
        if (RELU) v = fmaxf(v, 0.0f);
        if (RES)  v += R[row * N + col];
        if (OT == 0) ((float*)Cout)[row * N + col] = v;
        else ((unsigned short*)Cout)[row * N + col] = f2bf(v);
      }
    }
  }
}

// ---------------------------------------------------------------- flash attention (bf16 MFMA, KVBLK=128)
__global__ __launch_bounds__(256) void k_fattn(
    const unsigned short* __restrict__ QKV, unsigned short* __restrict__ O) {
  __shared__ unsigned short Ks[128][72];     // [k][d] 144B rows
  __shared__ unsigned short Vs[64][136];     // [d][k] transposed, 272B rows
  __shared__ unsigned short Pl[4][32][136];  // per-wave P transpose
  int tid = threadIdx.x;
  int lane = tid & 63, wid = tid >> 6;
  int lr = lane & 15, lq = lane >> 4;
  int qt = blockIdx.x, bh = blockIdx.y;
  int b = bh >> 4, h = bh & 15;
  size_t base = ((size_t)b * T_) * QKVS_ + h * HS_;
  int q0w = qt * 128 + wid * 32;

  short8 qf[2][2];
  #pragma unroll
  for (int g = 0; g < 2; ++g)
    #pragma unroll
    for (int s = 0; s < 2; ++s)
      qf[g][s] = *(const short8*)(QKV + base + (size_t)(q0w + g * 16 + lr) * QKVS_ + s * 32 + lq * 8);

  f32x4 o_acc[2][4] = {};
  float mrun[2][4], lrun[2][4];
  #pragma unroll
  for (int g = 0; g < 2; ++g)
    #pragma unroll
    for (int i = 0; i < 4; ++i) { mrun[g][i] = -1e30f; lrun[g][i] = 0.0f; }
  const float sc = 0.03125f * 1.44269504f;
  int r = tid >> 2, cc = (tid & 3) * 16;
  int ntiles = qt + 1;

  uint4 kA0, kA1, kB0, kB1, vA0, vA1, vB0, vB1;
  {
    const unsigned short* kp = QKV + base + 1024 + (size_t)r * QKVS_ + cc;
    kA0 = *(const uint4*)kp; kA1 = *(const uint4*)(kp + 8);
    vA0 = *(const uint4*)(kp + 1024); vA1 = *(const uint4*)(kp + 1032);
    const unsigned short* kp2 = kp + (size_t)64 * QKVS_;
    kB0 = *(const uint4*)kp2; kB1 = *(const uint4*)(kp2 + 8);
    vB0 = *(const uint4*)(kp2 + 1024); vB1 = *(const uint4*)(kp2 + 1032);
  }

  for (int t = 0; t < ntiles; ++t) {
    __syncthreads();                         // prev tile's LDS reads done
    *(uint4*)&Ks[r][cc] = kA0;
    *(uint4*)&Ks[r][cc + 8] = kA1;
    *(uint4*)&Ks[64 + r][cc] = kB0;
    *(uint4*)&Ks[64 + r][cc + 8] = kB1;
    unsigned short vt[16];
    *(uint4*)&vt[0] = vA0; *(uint4*)&vt[8] = vA1;
    #pragma unroll
    for (int j = 0; j < 16; ++j) Vs[cc + j][r] = vt[j];
    *(uint4*)&vt[0] = vB0; *(uint4*)&vt[8] = vB1;
    #pragma unroll
    for (int j = 0; j < 16; ++j) Vs[cc + j][64 + r] = vt[j];
    __syncthreads();                         // staging visible
    if (t + 1 < ntiles) {                    // T14: hide next-tile HBM under compute
      const unsigned short* kp = QKV + base + 1024 + (size_t)((t + 1) * 128 + r) * QKVS_ + cc;
      kA0 = *(const uint4*)kp; kA1 = *(const uint4*)(kp + 8);
      vA0 = *(const uint4*)(kp + 1024); vA1 = *(const uint4*)(kp + 1032);
      const unsigned short* kp2 = kp + (size_t)64 * QKVS_;
      kB0 = *(const uint4*)kp2; kB1 = *(const uint4*)(kp2 + 8);
      vB0 = *(const uint4*)(kp2 + 1024); vB1 = *(const uint4*)(kp2 + 1032);
    }

    bool diag = (t == qt);
    float p[2][8][4];
    __builtin_amdgcn_s_setprio(1);           // T5: favor QK^T MFMA cluster
    #pragma unroll
    for (int nt = 0; nt < 8; ++nt) {
      f32x4 s0 = {}, s1 = {};
      #pragma unroll
      for (int s = 0; s < 2; ++s) {
        short8 kf = *(const short8*)&Ks[nt * 16 + lr][s * 32 + lq * 8];
        s0 = __builtin_amdgcn_mfma_f32_16x16x32_bf16(qf[0][s], kf, s0, 0, 0, 0);
        s1 = __builtin_amdgcn_mfma_f32_16x16x32_bf16(qf[1][s], kf, s1, 0, 0, 0);
      }
      #pragma unroll
      for (int i = 0; i < 4; ++i) {
        float v0 = s0[i] * sc, v1 = s1[i] * sc;
        if (diag) {
          int col = t * 128 + nt * 16 + lr;
          if (col > q0w + lq * 4 + i) v0 = -1e30f;
          if (col > q0w + 16 + lq * 4 + i) v1 = -1e30f;
        }
        p[0][nt][i] = v0;
        p[1][nt][i] = v1;
      }
    }
    __builtin_amdgcn_s_setprio(0);
    #pragma unroll
    for (int g = 0; g < 2; ++g)
      #pragma unroll
      for (int i = 0; i < 4; ++i) {
        float v = fmaxf(fmaxf(fmaxf(p[g][0][i], p[g][1][i]), fmaxf(p[g][2][i], p[g][3][i])),
                        fmaxf(fmaxf(p[g][4][i], p[g][5][i]), fmaxf(p[g][6][i], p[g][7][i])));
        #pragma unroll
        for (int o = 1; o < 16; o <<= 1) v = fmaxf(v, __shfl_xor(v, o));
        if (v > mrun[g][i] + 10.0f) {        // T13 defer-max
          float corr = __builtin_amdgcn_exp2f(mrun[g][i] - v);
          mrun[g][i] = v;
          lrun[g][i] *= corr;
          #pragma unroll
          for (int dn = 0; dn < 4; ++dn) o_acc[g][dn][i] *= corr;
        }
        float mn = mrun[g][i];
        float ps = 0.0f;
        #pragma unroll
        for (int nt = 0; nt < 8; ++nt) {
          float pe = __builtin_amdgcn_exp2f(p[g][nt][i] - mn);
          p[g][nt][i] = pe;
          ps += pe;
        }
        lrun[g][i] += ps;
      }
    // P -> per-wave LDS transpose; intra-wave DS ordering suffices (no barrier)
    #pragma unroll
    for (int g = 0; g < 2; ++g)
      #pragma unroll
      for (int nt = 0; nt < 8; ++nt)
        #pragma unroll
        for (int i = 0; i < 4; ++i)
          Pl[wid][g * 16 + lq * 4 + i][nt * 16 + lr] = f2bf(p[g][nt][i]);

    __builtin_amdgcn_s_setprio(1);           // T5: favor PV MFMA cluster
    #pragma unroll
    for (int s = 0; s < 4; ++s) {
      short8 pa0 = *(const short8*)&Pl[wid][lr][s * 32 + lq * 8];
      short8 pa1 = *(const short8*)&Pl[wid][16 + lr][s * 32 + lq * 8];
      #pragma unroll
      for (int dn = 0; dn < 4; ++dn) {
        short8 vf = *(const short8*)&Vs[dn * 16 + lr][s * 32 + lq * 8];
        o_acc[0][dn] = __builtin_amdgcn_mfma_f32_16x16x32_bf16(pa0, vf, o_acc[0][dn], 0, 0, 0);
        o_acc[1][dn] = __builtin_amdgcn_mfma_f32_16x16x32_bf16(pa1, vf, o_acc[1][dn], 0, 0, 0);
      }
    }
    __builtin_amdgcn_s_setprio(0);
  }

  #pragma unroll
  for (int g = 0; g < 2; ++g)
    #pragma unroll
    for (int i = 0; i < 4; ++i) {
      float v = lrun[g][i];
      #pragma unroll
      for (int o = 1; o < 16; o <<= 1) v += __shfl_xor(v, o);
      lrun[g][i] = 1.0f / v;
    }
  #pragma unroll
  for (int g = 0; g < 2; ++g)
    #pragma unroll
    for (int dn = 0; dn < 4; ++dn)
      #pragma unroll
      for (int i = 0; i < 4; ++i) {
        size_t row = (size_t)(b * T_) + q0w + g * 16 + lq * 4 + i;
        O[row * E_ + h * HS_ + dn * 16 + lr] = f2bf(o_acc[g][dn][i] * lrun[g][i]);
      }
}

// ---------------------------------------------------------------- launch
extern "C" void kernel_launch(void* const* d_in, const int* in_sizes, int n_in,
                              void* d_out, int out_size, void* d_ws, size_t ws_size,
                              hipStream_t stream) {
  const int*   idx  = (const int*)d_in[0];
  const float* tok  = (const float*)d_in[1];
  const float* pos  = (const float*)d_in[2];
  const float* ln1g = (const float*)d_in[3];
  const float* ln1b = (const float*)d_in[4];
  const float* Wq   = (const float*)d_in[5];
  const float* Wk   = (const float*)d_in[6];
  const float* Wv   = (const float*)d_in[7];
  const float* Wo   = (const float*)d_in[8];
  const float* bo   = (const float*)d_in[9];
  const float* ln2g = (const float*)d_in[10];
  const float* ln2b = (const float*)d_in[11];
  const float* W1   = (const float*)d_in[12];
  const float* b1   = (const float*)d_in[13];
  const float* W2   = (const float*)d_in[14];
  const float* b2   = (const float*)d_in[15];
  const float* lnfg = (const float*)d_in[16];
  const float* lnfb = (const float*)d_in[17];
  const float* Wlm  = (const float*)d_in[18];
  const float* blm  = (const float*)d_in[19];

  char* scr = (char*)d_out;
  const size_t MB = 1024 * 1024;
  float*          xf    = (float*)(scr);                      // 16MB
  unsigned short* qkvb  = (unsigned short*)(scr + 16 * MB);   // 24MB
  unsigned short* ob    = (unsigned short*)(scr + 40 * MB);   // 8MB
  unsigned short* mh    = (unsigned short*)(scr + 48 * MB);   // 32MB
  unsigned short* wqkvT = (unsigned short*)(scr + 80 * MB);   // 48MB
  unsigned short* woT   = (unsigned short*)(scr + 128 * MB);  // 16MB
  unsigned short* w1T   = (unsigned short*)(scr + 144 * MB);  // 64MB
  unsigned short* w2T   = (unsigned short*)(scr + 208 * MB);  // 64MB
  unsigned short* p2    = (unsigned short*)(scr + 280 * MB);  // 32MB split-K bf16 partials
  unsigned short* hb    = (unsigned short*)d_ws;              // 8MB
  unsigned short* wlmT  = (unsigned short*)((char*)d_ws + 8 * MB); // 65.5MB
  const size_t EE = (size_t)E_ * E_;
  bool lm_fast = ws_size >= 8 * MB + (size_t)V_ * E_ * 2 + 1024;

  k_embed<<<M_, 256, 0, stream>>>(idx, tok, pos, xf);

  k_wt<<<dim3(16, 16, L_), 256, 0, stream>>>(Wq, wqkvT,          E_, E_, EE, 3 * EE);
  k_wt<<<dim3(16, 16, L_), 256, 0, stream>>>(Wk, wqkvT + EE,     E_, E_, EE, 3 * EE);
  k_wt<<<dim3(16, 16, L_), 256, 0, stream>>>(Wv, wqkvT + 2 * EE, E_, E_, EE, 3 * EE);
  k_wt<<<dim3(16, 16, L_), 256, 0, stream>>>(Wo, woT,            E_, E_, EE, EE);
  k_wt<<<dim3(64, 16, L_), 256, 0, stream>>>(W1, w1T, E_, 4 * E_, 4 * EE, 4 * EE);
  k_wt<<<dim3(16, 64, L_), 256, 0, stream>>>(W2, w2T, 4 * E_, E_, 4 * EE, 4 * EE);
  if (lm_fast)
    k_wt<<<dim3(V_ / 64, 16, 1), 256, 0, stream>>>(Wlm, wlmT, E_, V_, 0, 0);

  // ln1 of layer 0; subsequent LNs: ln2 standalone, ln1(l+1)/lnf fused into k_red4ln
  k_ln_bf<<<M_, 256, 0, stream>>>(xf, ln1g, ln1b, hb);

  for (int l = 0; l < L_; ++l) {
    // QKV: 256x192 tile -> 256 blocks (full CU utilization)
    k_gemm_256<1, false, 0, 3><<<16 * (QKVS_ / 192), 512, 0, stream>>>(
        hb, wqkvT + (size_t)l * 3 * EE, nullptr, qkvb, QKVS_, E_, E_);
    k_fattn<<<dim3(T_ / 128, B_ * H_), 256, 0, stream>>>(qkvb, ob);
    k_gemm_tn<64, 0, false, true><<<dim3(32, 16), 256, 0, stream>>>(
        ob, woT + (size_t)l * EE, bo + l * E_, xf, xf, M_, E_, E_);
    k_ln_bf<<<M_, 256, 0, stream>>>(xf, ln2g + l * E_, ln2b + l * E_, hb);
    k_gemm_256<1, true, 0, 4><<<16 * (4 * E_ / 256), 512, 0, stream>>>(
        hb, w1T + (size_t)l * 4 * EE, b1 + (size_t)l * 4 * E_, mh, 4 * E_, E_, E_);
    // MLP2: split-K=4 -> bf16 partials -> fused reduce(+b2+residual) + next-layer LN
    k_gemm_256<1, false, 2, 4><<<256, 512, 0, stream>>>(
        mh, w2T + (size_t)l * 4 * EE, nullptr, p2, E_, E_, 4 * E_);
    const float* ng = (l + 1 < L_) ? (ln1g + (size_t)(l + 1) * E_) : lnfg;
    const float* nb = (l + 1 < L_) ? (ln1b + (size_t)(l + 1) * E_) : lnfb;
    k_red4ln<<<M_, 256, 0, stream>>>(p2, b2 + l * E_, xf, ng, nb, hb);
  }
  // hb now holds lnf(x)
  if (lm_fast)
    k_gemm_256<0, false, 1, 4><<<16 * (V_ / 256), 512, 0, stream>>>(
        hb, wlmT, blm, (float*)d_out, V_, E_, E_);
  else
    k_gemm_bf<0, false, false><<<dim3(32, V_ / 128), 256, 0, stream>>>(
        hb, Wlm, blm, nullptr, (float*)d_out, M_, V_, E_);
}

// Round 17
// 2355.130 us; speedup vs baseline: 1.0556x; 1.0166x over previous
//
#include <hip/hip_runtime.h>
#include <math.h>

#define L_ 8
#define H_ 16
#define E_ 1024
#define V_ 32000
#define B_ 4
#define T_ 1024
#define HS_ 64
#define M_ 4096   // B*T
#define QKVS_ 3072  // fused qkv row stride

typedef __attribute__((ext_vector_type(8))) short short8;
typedef __attribute__((ext_vector_type(4))) float f32x4;

__device__ __forceinline__ unsigned short f2bf(float f) {
  unsigned int u = __builtin_bit_cast(unsigned int, f);
  u += 0x7fffu + ((u >> 16) & 1u);          // RNE
  return (unsigned short)(u >> 16);
}
__device__ __forceinline__ float bf2f(unsigned short u) {
  unsigned int v = ((unsigned int)u) << 16;
  return __builtin_bit_cast(float, v);
}

// ---------------------------------------------------------------- embed (fp32 x)
__global__ __launch_bounds__(256) void k_embed(
    const int* __restrict__ idx, const float* __restrict__ tok,
    const float* __restrict__ pos, float* __restrict__ x) {
  int bt = blockIdx.x;
  int t  = bt & (T_ - 1);
  int token = idx[bt];
  const float4* te = (const float4*)(tok + (size_t)token * E_);
  const float4* pe = (const float4*)(pos + (size_t)t * E_);
  float4* xo = (float4*)(x + (size_t)bt * E_);
  int i = threadIdx.x;
  float4 a = te[i], b = pe[i];
  xo[i] = make_float4(a.x + b.x, a.y + b.y, a.z + b.z, a.w + b.w);
}

// ---------------------------------------------------------------- weight transpose+convert (vectorized)
__global__ __launch_bounds__(256) void k_wt(
    const float* __restrict__ W, unsigned short* __restrict__ WT,
    int K, int N, size_t ss, size_t ds) {
  __shared__ unsigned short t[64][68];
  const float* Ws = W + (size_t)blockIdx.z * ss;
  unsigned short* Wd = WT + (size_t)blockIdx.z * ds;
  int n0 = blockIdx.x * 64, k0 = blockIdx.y * 64;
  int tid = threadIdx.x;
  int c4 = (tid & 15) * 4, r16 = tid >> 4;
  #pragma unroll
  for (int i = 0; i < 4; ++i) {
    int kr = i * 16 + r16;
    float4 v = *(const float4*)&Ws[(size_t)(k0 + kr) * N + n0 + c4];
    ushort4 pk;
    pk.x = f2bf(v.x); pk.y = f2bf(v.y); pk.z = f2bf(v.z); pk.w = f2bf(v.w);
    *(ushort4*)&t[kr][c4] = pk;
  }
  __syncthreads();
  #pragma unroll
  for (int i = 0; i < 4; ++i) {
    int nr = i * 16 + r16;
    ushort4 o;
    o.x = t[c4 + 0][nr]; o.y = t[c4 + 1][nr];
    o.z = t[c4 + 2][nr]; o.w = t[c4 + 3][nr];
    *(ushort4*)&Wd[(size_t)(n0 + nr) * K + k0 + c4] = o;
  }
}

// ---------------------------------------------------------------- layernorm (fp32 in, bf16 out)
__device__ __forceinline__ float blk_sum256(float v, float* red) {
  #pragma unroll
  for (int o = 1; o < 64; o <<= 1) v += __shfl_xor(v, o);
  int wid = threadIdx.x >> 6, lane = threadIdx.x & 63;
  if (lane == 0) red[wid] = v;
  __syncthreads();
  v = red[0] + red[1] + red[2] + red[3];
  __syncthreads();
  return v;
}

__global__ __launch_bounds__(256) void k_ln_bf(
    const float* __restrict__ X, const float* __restrict__ g,
    const float* __restrict__ b, unsigned short* __restrict__ Y) {
  __shared__ float red[4];
  int row = blockIdx.x;
  int i = threadIdx.x;
  float4 xv = ((const float4*)(X + (size_t)row * E_))[i];
  float s = xv.x + xv.y + xv.z + xv.w;
  s = blk_sum256(s, red);
  float mean = s * (1.0f / E_);
  float dx = xv.x - mean, dy = xv.y - mean, dz = xv.z - mean, dw = xv.w - mean;
  float vs = dx*dx + dy*dy + dz*dz + dw*dw;
  vs = blk_sum256(vs, red);
  float rstd = rsqrtf(vs * (1.0f / E_) + 1e-5f);
  float4 gv = ((const float4*)g)[i];
  float4 bv = ((const float4*)b)[i];
  ushort4 o;
  o.x = f2bf(dx * rstd * gv.x + bv.x);
  o.y = f2bf(dy * rstd * gv.y + bv.y);
  o.z = f2bf(dz * rstd * gv.z + bv.z);
  o.w = f2bf(dw * rstd * gv.w + bv.w);
  ((ushort4*)(Y + (size_t)row * E_))[i] = o;
}

// ---------------------------------------------------------------- fused split-K reduce + residual + next-LN
__global__ __launch_bounds__(256) void k_red4ln(
    const unsigned short* __restrict__ p, const float* __restrict__ bias,
    float* __restrict__ xf, const float* __restrict__ g,
    const float* __restrict__ b, unsigned short* __restrict__ hb) {
  __shared__ float red[4];
  const int ME = M_ * E_;
  int row = blockIdx.x;
  int tid = threadIdx.x;
  int i = row * E_ + tid * 4;
  ushort4 a  = *(const ushort4*)(p + i);
  ushort4 b2 = *(const ushort4*)(p + ME + i);
  ushort4 c  = *(const ushort4*)(p + 2 * ME + i);
  ushort4 d  = *(const ushort4*)(p + 3 * ME + i);
  float4 bv = *(const float4*)(bias + tid * 4);
  float4 x  = *(float4*)(xf + i);
  x.x += bf2f(a.x) + bf2f(b2.x) + bf2f(c.x) + bf2f(d.x) + bv.x;
  x.y += bf2f(a.y) + bf2f(b2.y) + bf2f(c.y) + bf2f(d.y) + bv.y;
  x.z += bf2f(a.z) + bf2f(b2.z) + bf2f(c.z) + bf2f(d.z) + bv.z;
  x.w += bf2f(a.w) + bf2f(b2.w) + bf2f(c.w) + bf2f(d.w) + bv.w;
  *(float4*)(xf + i) = x;
  float s = x.x + x.y + x.z + x.w;
  s = blk_sum256(s, red);
  float mean = s * (1.0f / E_);
  float dx = x.x - mean, dy = x.y - mean, dz = x.z - mean, dw = x.w - mean;
  float vs = dx*dx + dy*dy + dz*dz + dw*dw;
  vs = blk_sum256(vs, red);
  float rstd = rsqrtf(vs * (1.0f / E_) + 1e-5f);
  float4 gv = ((const float4*)g)[tid];
  float4 lb = ((const float4*)b)[tid];
  ushort4 o;
  o.x = f2bf(dx * rstd * gv.x + lb.x);
  o.y = f2bf(dy * rstd * gv.y + lb.y);
  o.z = f2bf(dz * rstd * gv.z + lb.z);
  o.w = f2bf(dw * rstd * gv.w + lb.w);
  ((ushort4*)(hb + (size_t)row * E_))[tid] = o;
}

#define GLDS(src, dst) __builtin_amdgcn_global_load_lds( \
    (const __attribute__((address_space(1))) void*)(src), \
    (__attribute__((address_space(3))) void*)(dst), 16, 0, 0)

#define BAR() do { asm volatile("" ::: "memory"); __builtin_amdgcn_s_barrier(); \
                   asm volatile("" ::: "memory"); } while (0)

// ---------------------------------------------------------------- 256xBN 8-phase bf16 GEMM (BK=64)
// DEC: 0 = m-fastest, 1 = LM head (msub8-fastest), 2 = split-K=4 partials.
template<int OT, bool RELU, int DEC, int NF>
__global__ __launch_bounds__(512, 2) void k_gemm_256(
    const unsigned short* __restrict__ A, const unsigned short* __restrict__ BT,
    const float* __restrict__ bias, void* __restrict__ Cout, int N, int K, int Kstr) {
  constexpr int BUFA = 16384;        // 256*64
  constexpr int BUFB = NF * 4096;    // BN*64
  constexpr int BN = NF * 64;
  __shared__ __attribute__((aligned(16))) unsigned short As[2 * BUFA];
  __shared__ __attribute__((aligned(16))) unsigned short Bs[2 * BUFB];
  int tid = threadIdx.x;
  int lane = tid & 63, w = tid >> 6;           // 8 waves
  int lr = lane & 15, lq = (lane >> 4) & 3;
  int wm = w >> 2, wn = w & 3;                 // 2 x 4 wave grid

  // bijective XCD swizzle (m204)
  int nwg = gridDim.x, orig = blockIdx.x;
  int qq = nwg >> 3, rr = nwg & 7;
  int xcd = orig & 7, lid = orig >> 3;
  int wg = (xcd < rr ? xcd * (qq + 1) : rr * (qq + 1) + (xcd - rr) * qq) + lid;
  int m0, n0, kofs = 0;
  size_t cofs = 0;
  if constexpr (DEC == 0) { m0 = (wg & 15) * 256; n0 = (wg >> 4) * BN; }
  else if constexpr (DEC == 1) {
    int nbn = N / BN;
    int msub = wg & 7;
    int rest = wg >> 3;
    int nb = rest % nbn;
    int msup = rest / nbn;
    m0 = (msup * 8 + msub) * 256;
    n0 = nb * BN;
  } else {
    int inner = wg & 63;
    m0 = (inner & 15) * 256; n0 = (inner >> 4) * BN;
    int ks = wg >> 6;
    kofs = ks * K;
    cofs = (size_t)ks * M_ * (size_t)N;
  }

  // staging: chunk swizzle c8_src = (lane&7) ^ (lane>>3); dest linear
  int srow = w * 8 + (lane >> 3);
  int skoff = ((lane & 7) ^ (lane >> 3)) * 8;
  const unsigned short* aS = A + (size_t)(m0 + srow) * Kstr + kofs + skoff;
  const unsigned short* bS = BT + (size_t)(n0 + srow) * Kstr + kofs + skoff;

#define STG_A1(bo, g, tt) GLDS(aS + (size_t)((g) * 64) * Kstr + (tt) * 64, \
                               &As[(bo) + (((g) * 64) << 6) + (w << 9)])
#define STG_B1(bo, g, tt) GLDS(bS + (size_t)((g) * 64) * Kstr + (tt) * 64, \
                               &Bs[(bo) + (((g) * 64) << 6) + (w << 9)])
#define LDA_(dst, mh, ks) { _Pragma("unroll") for (int m_ = 0; m_ < 4; ++m_) \
  dst[m_] = *(const short8*)&As[soA + ((wm * 128 + (mh) * 64 + m_ * 16 + lr) << 6) + ((((ks) * 4 + lq) ^ (lr & 7)) << 3)]; }
#define LDB_(dst, ks) { _Pragma("unroll") for (int n_ = 0; n_ < NF; ++n_) \
  dst[n_] = *(const short8*)&Bs[soB + ((wn * (16 * NF) + n_ * 16 + lr) << 6) + ((((ks) * 4 + lq) ^ (lr & 7)) << 3)]; }
#define MMA(afr, mofs) do { __builtin_amdgcn_s_setprio(1); \
  _Pragma("unroll") for (int m_ = 0; m_ < 4; ++m_) { \
    _Pragma("unroll") for (int n_ = 0; n_ < NF; ++n_) \
      acc[(mofs) + m_][n_] = __builtin_amdgcn_mfma_f32_16x16x32_bf16(afr[m_], bfr[n_], acc[(mofs) + m_][n_], 0, 0, 0); } \
  __builtin_amdgcn_s_setprio(0); } while (0)

  f32x4 acc[8][NF] = {};
  const int NT = K >> 6;

  // prologue: tile0 full (4+NF loads) + B(t1) g0,g1 -> vmcnt(2)
  #pragma unroll
  for (int g = 0; g < 4; ++g) STG_A1(0, g, 0);
  #pragma unroll
  for (int g = 0; g < NF; ++g) STG_B1(0, g, 0);
  if (NT > 1) {
    STG_B1(BUFB, 0, 1); STG_B1(BUFB, 1, 1);
    asm volatile("s_waitcnt vmcnt(2)" ::: "memory");
  } else {
    asm volatile("s_waitcnt vmcnt(0)" ::: "memory");
  }
  BAR();

  for (int t = 0; t < NT; ++t) {
    const int soA = (t & 1) * BUFA, soB = (t & 1) * BUFB;
    const int nbA = ((t + 1) & 1) * BUFA, nbB = ((t + 1) & 1) * BUFB;
    short8 af0[4], af1[4], bfr[NF];
    // ---- P0: stage B-hi(t+1) -> idle
    LDA_(af0, 0, 0);
    LDB_(bfr, 0);
    if (t + 1 < NT) {
      STG_B1(nbB, 2, t + 1);
      if constexpr (NF == 4) STG_B1(nbB, 3, t + 1);
    }
    BAR(); MMA(af0, 0); BAR();
    // ---- P1: stage A-lo(t+1) -> idle
    LDA_(af1, 1, 0);
    if (t + 1 < NT) { STG_A1(nbA, 0, t + 1); STG_A1(nbA, 1, t + 1); }
    BAR(); MMA(af1, 4); BAR();
    // ---- P2: stage A-hi(t+1) -> idle
    LDA_(af0, 0, 1);
    LDB_(bfr, 1);
    if (t + 1 < NT) { STG_A1(nbA, 2, t + 1); STG_A1(nbA, 3, t + 1); }
    BAR(); MMA(af0, 0); BAR();
    // ---- P3: stage B-lo(t+2) -> current buffer B region (dead after P2)
    LDA_(af1, 1, 1);
    if (t + 2 < NT) { STG_B1(soB, 0, t + 2); STG_B1(soB, 1, t + 2); }
    BAR(); MMA(af1, 4);
    if (t + 2 < NT) { asm volatile("s_waitcnt vmcnt(2)" ::: "memory"); }
    else            { asm volatile("s_waitcnt vmcnt(0)" ::: "memory"); }
    BAR();
  }

  #pragma unroll
  for (int m = 0; m < 8; ++m) {
    #pragma unroll
    for (int n = 0; n < NF; ++n) {
      int col = n0 + wn * (16 * NF) + n * 16 + lr;
      float bv = bias ? bias[col] : 0.0f;
      #pragma unroll
      for (int i = 0; i < 4; ++i) {
        size_t row = (size_t)(m0 + wm * 128 + m * 16 + lq * 4 + i);
        float v = acc[m][n][i] + bv;
        if (RELU) v = fmaxf(v, 0.0f);
        if (OT == 0) ((float*)Cout)[cofs + row * N + col] = v;
        else ((unsigned short*)Cout)[cofs + row * N + col] = f2bf(v);
      }
    }
  }
#undef STG_A1
#undef STG_B1
#undef LDA_
#undef LDB_
#undef MMA
}

// ---------------------------------------------------------------- bf16 TN MFMA GEMM (2-phase, BN<=128)
template<int BN, int OT, bool RELU, bool RES>
__global__ __launch_bounds__(256) void k_gemm_tn(
    const unsigned short* __restrict__ A, const unsigned short* __restrict__ BT,
    const float* __restrict__ bias, const float* __restrict__ R,
    void* __restrict__ Cout, int M, int N, int K) {
  constexpr int NF = BN / 32;
  __shared__ __attribute__((aligned(16))) unsigned short As[128 * 64];
  __shared__ __attribute__((aligned(16))) unsigned short Bs[BN * 64];
  int tid = threadIdx.x;
  int lane = tid & 63, w = tid >> 6;
  int lr = lane & 15, lq = lane >> 4;
  int m0 = blockIdx.x * 128, n0 = blockIdx.y * BN;
  int wr = (w >> 1) * 64, wc = (w & 1) * (BN / 2);

  int srow = w * 8 + (lane >> 3);
  int skoff = ((lane & 7) ^ (lane >> 3)) * 8;
  const unsigned short* a0 = A + (size_t)(m0 + srow) * K + skoff;
  const unsigned short* b0 = BT + (size_t)(n0 + srow) * K + skoff;

  f32x4 acc[4][NF] = {};

  for (int k0 = 0; k0 < K; k0 += 64) {
    __syncthreads();
    #pragma unroll
    for (int j = 0; j < 4; ++j)
      __builtin_amdgcn_global_load_lds(
          (const __attribute__((address_space(1))) void*)(a0 + (size_t)(j * 32) * K + k0),
          (__attribute__((address_space(3))) void*)(As + j * 2048 + w * 512), 16, 0, 0);
    #pragma unroll
    for (int j = 0; j < NF; ++j)
      __builtin_amdgcn_global_load_lds(
          (const __attribute__((address_space(1))) void*)(b0 + (size_t)(j * 32) * K + k0),
          (__attribute__((address_space(3))) void*)(Bs + j * 2048 + w * 512), 16, 0, 0);
    __syncthreads();
    short8 af[4][2], bf[NF][2];
    #pragma unroll
    for (int m = 0; m < 4; ++m)
      #pragma unroll
      for (int ks = 0; ks < 2; ++ks)
        af[m][ks] = *(const short8*)&As[(wr + m * 16 + lr) * 64 + (((ks * 4 + lq) ^ (lr & 7)) << 3)];
    #pragma unroll
    for (int n = 0; n < NF; ++n)
      #pragma unroll
      for (int ks = 0; ks < 2; ++ks)
        bf[n][ks] = *(const short8*)&Bs[(wc + n * 16 + lr) * 64 + (((ks * 4 + lq) ^ (lr & 7)) << 3)];
    #pragma unroll
    for (int ks = 0; ks < 2; ++ks)
      #pragma unroll
      for (int m = 0; m < 4; ++m)
        #pragma unroll
        for (int n = 0; n < NF; ++n)
          acc[m][n] = __builtin_amdgcn_mfma_f32_16x16x32_bf16(af[m][ks], bf[n][ks], acc[m][n], 0, 0, 0);
  }

  #pragma unroll
  for (int m = 0; m < 4; ++m) {
    #pragma unroll
    for (int n = 0; n < NF; ++n) {
      int col = n0 + wc + n * 16 + lr;
      float bv = bias ? bias[col] : 0.0f;
      #pragma unroll
      for (int i = 0; i < 4; ++i) {
        size_t row = (size_t)(m0 + wr + m * 16 + lq * 4 + i);
        float v = acc[m][n][i] + bv;
        if (RELU) v = fmaxf(v, 0.0f);
        if (RES)  v += R[row * N + col];
        if (OT == 0) ((float*)Cout)[row * N + col] = v;
        else ((unsigned short*)Cout)[row * N + col] = f2bf(v);
      }
    }
  }
}

// ---------------------------------------------------------------- legacy GEMM (fp32 B) for LM fallback
template<int OT, bool RELU, bool RES>
__global__ __launch_bounds__(256) void k_gemm_bf(
    const unsigned short* __restrict__ A, const float* __restrict__ W,
    const float* __restrict__ bias, const float* __restrict__ R,
    void* __restrict__ Cout, int M, int N, int K) {
  __shared__ unsigned short As[128][40];
  __shared__ unsigned short Bs[128][40];
  int tid = threadIdx.x;
  int lane = tid & 63, wid = tid >> 6;
  int m0 = blockIdx.x * 128, n0 = blockIdx.y * 128;
  int wr = (wid >> 1) * 64, wc = (wid & 1) * 64;
  f32x4 acc[4][4] = {};
  int a_row = tid >> 1, a_koff = (tid & 1) * 16;
  int b_nb = tid & 31, b_kb = (tid >> 5) * 4;
  int lr = lane & 15, lq = lane >> 4;
  for (int k0 = 0; k0 < K; k0 += 32) {
    const unsigned short* ap = A + (size_t)(m0 + a_row) * K + k0 + a_koff;
    uint4 av0 = *(const uint4*)ap;
    uint4 av1 = *(const uint4*)(ap + 8);
    float wv[4][4];
    #pragma unroll
    for (int dk = 0; dk < 4; ++dk) {
      const float* wrow = W + (size_t)(k0 + b_kb + dk) * N + n0 + b_nb;
      #pragma unroll
      for (int j = 0; j < 4; ++j) wv[j][dk] = wrow[32 * j];
    }
    __syncthreads();
    *(uint4*)&As[a_row][a_koff]     = av0;
    *(uint4*)&As[a_row][a_koff + 8] = av1;
    #pragma unroll
    for (int j = 0; j < 4; ++j) {
      ushort4 pk;
      pk.x = f2bf(wv[j][0]); pk.y = f2bf(wv[j][1]);
      pk.z = f2bf(wv[j][2]); pk.w = f2bf(wv[j][3]);
      *(ushort4*)&Bs[b_nb + 32 * j][b_kb] = pk;
    }
    __syncthreads();
    short8 af[4], bf[4];
    #pragma unroll
    for (int m = 0; m < 4; ++m) af[m] = *(const short8*)&As[wr + m * 16 + lr][lq * 8];
    #pragma unroll
    for (int n = 0; n < 4; ++n) bf[n] = *(const short8*)&Bs[wc + n * 16 + lr][lq * 8];
    #pragma unroll
    for (int m = 0; m < 4; ++m)
      #pragma unroll
      for (int n = 0; n < 4; ++n)
        acc[m][n] = __builtin_amdgcn_mfma_f32_16x16x32_bf16(af[m], bf[n], acc[m][n], 0, 0, 0);
  }
  #pragma unroll
  for (int m = 0; m < 4; ++m) {
    #pragma unroll
    for (int n = 0; n < 4; ++n) {
      int col = n0 + wc + n * 16 + lr;
      float bv = bias ? bias[col] : 0.0f;
      #pragma unroll
      for (int i = 0; i < 4; ++i) {
        size_t row = (size_t)(m0 + wr + m * 16 + lq * 4 + i);
        float v = acc[m][n][i] + bv;
        if (RELU) v = fmaxf(v, 0.0f);
        if (RES)  v += R[row * N + col];
        if (OT == 0) ((float*)Cout)[row * N + col] = v;
        else ((unsigned short*)Cout)[row * N + col] = f2bf(v);
      }
    }
  }
}

// ---------------------------------------------------------------- flash attention (bf16 MFMA, KVBLK=128)
// Load-balanced 1-D grid of 512: block f -> (qt,bh) such that co-resident
// pairs (f, f+256) have qt + qt' = 7 (uniform ~9 tile-units per CU).
__global__ __launch_bounds__(256) void k_fattn(
    const unsigned short* __restrict__ QKV, unsigned short* __restrict__ O) {
  __shared__ unsigned short Ks[128][72];     // [k][d] 144B rows
  __shared__ unsigned short Vs[64][136];     // [d][k] transposed, 272B rows
  __shared__ unsigned short Pl[4][32][136];  // per-wave P transpose
  int tid = threadIdx.x;
  int lane = tid & 63, wid = tid >> 6;
  int lr = lane & 15, lq = lane >> 4;
  int f = blockIdx.x;
  int half = f >> 8, rm = f & 255;
  int qt = half ? 7 - (rm & 3) : (rm & 3);
  int bh = rm >> 2;
  int b = bh >> 4, h = bh & 15;
  size_t base = ((size_t)b * T_) * QKVS_ + h * HS_;
  int q0w = qt * 128 + wid * 32;

  short8 qf[2][2];
  #pragma unroll
  for (int g = 0; g < 2; ++g)
    #pragma unroll
    for (int s = 0; s < 2; ++s)
      qf[g][s] = *(const short8*)(QKV + base + (size_t)(q0w + g * 16 + lr) * QKVS_ + s * 32 + lq * 8);

  f32x4 o_acc[2][4] = {};
  float mrun[2][4], lrun[2][4];
  #pragma unroll
  for (int g = 0; g < 2; ++g)
    #pragma unroll
    for (int i = 0; i < 4; ++i) { mrun[g][i] = -1e30f; lrun[g][i] = 0.0f; }
  const float sc = 0.03125f * 1.44269504f;
  int r = tid >> 2, cc = (tid & 3) * 16;
  int ntiles = qt + 1;

  uint4 kA0, kA1, kB0, kB1, vA0, vA1, vB0, vB1;
  {
    const unsigned short* kp = QKV + base + 1024 + (size_t)r * QKVS_ + cc;
    kA0 = *(const uint4*)kp; kA1 = *(const uint4*)(kp + 8);
    vA0 = *(const uint4*)(kp + 1024); vA1 = *(const uint4*)(kp + 1032);
    const unsigned short* kp2 = kp + (size_t)64 * QKVS_;
    kB0 = *(const uint4*)kp2; kB1 = *(const uint4*)(kp2 + 8);
    vB0 = *(const uint4*)(kp2 + 1024); vB1 = *(const uint4*)(kp2 + 1032);
  }

  for (int t = 0; t < ntiles; ++t) {
    __syncthreads();                         // prev tile's LDS reads done
    *(uint4*)&Ks[r][cc] = kA0;
    *(uint4*)&Ks[r][cc + 8] = kA1;
    *(uint4*)&Ks[64 + r][cc] = kB0;
    *(uint4*)&Ks[64 + r][cc + 8] = kB1;
    unsigned short vt[16];
    *(uint4*)&vt[0] = vA0; *(uint4*)&vt[8] = vA1;
    #pragma unroll
    for (int j = 0; j < 16; ++j) Vs[cc + j][r] = vt[j];
    *(uint4*)&vt[0] = vB0; *(uint4*)&vt[8] = vB1;
    #pragma unroll
    for (int j = 0; j < 16; ++j) Vs[cc + j][64 + r] = vt[j];
    __syncthreads();                         // staging visible
    if (t + 1 < ntiles) {                    // T14: hide next-tile HBM under compute
      const unsigned short* kp = QKV + base + 1024 + (size_t)((t + 1) * 128 + r) * QKVS_ + cc;
      kA0 = *(const uint4*)kp; kA1 = *(const uint4*)(kp + 8);
      vA0 = *(const uint4*)(kp + 1024); vA1 = *(const uint4*)(kp + 1032);
      const unsigned short* kp2 = kp + (size_t)64 * QKVS_;
      kB0 = *(const uint4*)kp2; kB1 = *(const uint4*)(kp2 + 8);
      vB0 = *(const uint4*)(kp2 + 1024); vB1 = *(const uint4*)(kp2 + 1032);
    }

    bool diag = (t == qt);
    float p[2][8][4];
    __builtin_amdgcn_s_setprio(1);           // T5: favor QK^T MFMA cluster
    #pragma unroll
    for (int nt = 0; nt < 8; ++nt) {
      f32x4 s0 = {}, s1 = {};
      #pragma unroll
      for (int s = 0; s < 2; ++s) {
        short8 kf = *(const short8*)&Ks[nt * 16 + lr][s * 32 + lq * 8];
        s0 = __builtin_amdgcn_mfma_f32_16x16x32_bf16(qf[0][s], kf, s0, 0, 0, 0);
        s1 = __builtin_amdgcn_mfma_f32_16x16x32_bf16(qf[1][s], kf, s1, 0, 0, 0);
      }
      #pragma unroll
      for (int i = 0; i < 4; ++i) {
        float v0 = s0[i] * sc, v1 = s1[i] * sc;
        if (diag) {
          int col = t * 128 + nt * 16 + lr;
          if (col > q0w + lq * 4 + i) v0 = -1e30f;
          if (col > q0w + 16 + lq * 4 + i) v1 = -1e30f;
        }
        p[0][nt][i] = v0;
        p[1][nt][i] = v1;
      }
    }
    __builtin_amdgcn_s_setprio(0);
    #pragma unroll
    for (int g = 0; g < 2; ++g)
      #pragma unroll
      for (int i = 0; i < 4; ++i) {
        float v = fmaxf(fmaxf(fmaxf(p[g][0][i], p[g][1][i]), fmaxf(p[g][2][i], p[g][3][i])),
                        fmaxf(fmaxf(p[g][4][i], p[g][5][i]), fmaxf(p[g][6][i], p[g][7][i])));
        #pragma unroll
        for (int o = 1; o < 16; o <<= 1) v = fmaxf(v, __shfl_xor(v, o));
        if (v > mrun[g][i] + 10.0f) {        // T13 defer-max
          float corr = __builtin_amdgcn_exp2f(mrun[g][i] - v);
          mrun[g][i] = v;
          lrun[g][i] *= corr;
          #pragma unroll
          for (int dn = 0; dn < 4; ++dn) o_acc[g][dn][i] *= corr;
        }
        float mn = mrun[g][i];
        float ps = 0.0f;
        #pragma unroll
        for (int nt = 0; nt < 8; ++nt) {
          float pe = __builtin_amdgcn_exp2f(p[g][nt][i] - mn);
          p[g][nt][i] = pe;
          ps += pe;
        }
        lrun[g][i] += ps;
      }
    // P -> per-wave LDS transpose; intra-wave DS ordering suffices (no barrier)
    #pragma unroll
    for (int g = 0; g < 2; ++g)
      #pragma unroll
      for (int nt = 0; nt < 8; ++nt)
        #pragma unroll
        for (int i = 0; i < 4; ++i)
          Pl[wid][g * 16 + lq * 4 + i][nt * 16 + lr] = f2bf(p[g][nt][i]);

    __builtin_amdgcn_s_setprio(1);           // T5: favor PV MFMA cluster
    #pragma unroll
    for (int s = 0; s < 4; ++s) {
      short8 pa0 = *(const short8*)&Pl[wid][lr][s * 32 + lq * 8];
      short8 pa1 = *(const short8*)&Pl[wid][16 + lr][s * 32 + lq * 8];
      #pragma unroll
      for (int dn = 0; dn < 4; ++dn) {
        short8 vf = *(const short8*)&Vs[dn * 16 + lr][s * 32 + lq * 8];
        o_acc[0][dn] = __builtin_amdgcn_mfma_f32_16x16x32_bf16(pa0, vf, o_acc[0][dn], 0, 0, 0);
        o_acc[1][dn] = __builtin_amdgcn_mfma_f32_16x16x32_bf16(pa1, vf, o_acc[1][dn], 0, 0, 0);
      }
    }
    __builtin_amdgcn_s_setprio(0);
  }

  #pragma unroll
  for (int g = 0; g < 2; ++g)
    #pragma unroll
    for (int i = 0; i < 4; ++i) {
      float v = lrun[g][i];
      #pragma unroll
      for (int o = 1; o < 16; o <<= 1) v += __shfl_xor(v, o);
      lrun[g][i] = 1.0f / v;
    }
  #pragma unroll
  for (int g = 0; g < 2; ++g)
    #pragma unroll
    for (int dn = 0; dn < 4; ++dn)
      #pragma unroll
      for (int i = 0; i < 4; ++i) {
        size_t row = (size_t)(b * T_) + q0w + g * 16 + lq * 4 + i;
        O[row * E_ + h * HS_ + dn * 16 + lr] = f2bf(o_acc[g][dn][i] * lrun[g][i]);
      }
}

// ---------------------------------------------------------------- launch
extern "C" void kernel_launch(void* const* d_in, const int* in_sizes, int n_in,
                              void* d_out, int out_size, void* d_ws, size_t ws_size,
                              hipStream_t stream) {
  const int*   idx  = (const int*)d_in[0];
  const float* tok  = (const float*)d_in[1];
  const float* pos  = (const float*)d_in[2];
  const float* ln1g = (const float*)d_in[3];
  const float* ln1b = (const float*)d_in[4];
  const float* Wq   = (const float*)d_in[5];
  const float* Wk   = (const float*)d_in[6];
  const float* Wv   = (const float*)d_in[7];
  const float* Wo   = (const float*)d_in[8];
  const float* bo   = (const float*)d_in[9];
  const float* ln2g = (const float*)d_in[10];
  const float* ln2b = (const float*)d_in[11];
  const float* W1   = (const float*)d_in[12];
  const float* b1   = (const float*)d_in[13];
  const float* W2   = (const float*)d_in[14];
  const float* b2   = (const float*)d_in[15];
  const float* lnfg = (const float*)d_in[16];
  const float* lnfb = (const float*)d_in[17];
  const float* Wlm  = (const float*)d_in[18];
  const float* blm  = (const float*)d_in[19];

  char* scr = (char*)d_out;
  const size_t MB = 1024 * 1024;
  float*          xf    = (float*)(scr);                      // 16MB
  unsigned short* qkvb  = (unsigned short*)(scr + 16 * MB);   // 24MB
  unsigned short* ob    = (unsigned short*)(scr + 40 * MB);   // 8MB
  unsigned short* mh    = (unsigned short*)(scr + 48 * MB);   // 32MB
  unsigned short* wqkvT = (unsigned short*)(scr + 80 * MB);   // 48MB
  unsigned short* woT   = (unsigned short*)(scr + 128 * MB);  // 16MB
  unsigned short* w1T   = (unsigned short*)(scr + 144 * MB);  // 64MB
  unsigned short* w2T   = (unsigned short*)(scr + 208 * MB);  // 64MB
  unsigned short* p2    = (unsigned short*)(scr + 280 * MB);  // 32MB split-K bf16 partials
  unsigned short* hb    = (unsigned short*)d_ws;              // 8MB
  unsigned short* wlmT  = (unsigned short*)((char*)d_ws + 8 * MB); // 65.5MB
  const size_t EE = (size_t)E_ * E_;
  bool lm_fast = ws_size >= 8 * MB + (size_t)V_ * E_ * 2 + 1024;

  k_embed<<<M_, 256, 0, stream>>>(idx, tok, pos, xf);

  k_wt<<<dim3(16, 16, L_), 256, 0, stream>>>(Wq, wqkvT,          E_, E_, EE, 3 * EE);
  k_wt<<<dim3(16, 16, L_), 256, 0, stream>>>(Wk, wqkvT + EE,     E_, E_, EE, 3 * EE);
  k_wt<<<dim3(16, 16, L_), 256, 0, stream>>>(Wv, wqkvT + 2 * EE, E_, E_, EE, 3 * EE);
  k_wt<<<dim3(16, 16, L_), 256, 0, stream>>>(Wo, woT,            E_, E_, EE, EE);
  k_wt<<<dim3(64, 16, L_), 256, 0, stream>>>(W1, w1T, E_, 4 * E_, 4 * EE, 4 * EE);
  k_wt<<<dim3(16, 64, L_), 256, 0, stream>>>(W2, w2T, 4 * E_, E_, 4 * EE, 4 * EE);
  if (lm_fast)
    k_wt<<<dim3(V_ / 64, 16, 1), 256, 0, stream>>>(Wlm, wlmT, E_, V_, 0, 0);

  // ln1 of layer 0; subsequent LNs: ln2 standalone, ln1(l+1)/lnf fused into k_red4ln
  k_ln_bf<<<M_, 256, 0, stream>>>(xf, ln1g, ln1b, hb);

  for (int l = 0; l < L_; ++l) {
    // QKV: 256x192 tile -> 256 blocks (full CU utilization)
    k_gemm_256<1, false, 0, 3><<<16 * (QKVS_ / 192), 512, 0, stream>>>(
        hb, wqkvT + (size_t)l * 3 * EE, nullptr, qkvb, QKVS_, E_, E_);
    k_fattn<<<512, 256, 0, stream>>>(qkvb, ob);
    k_gemm_tn<64, 0, false, true><<<dim3(32, 16), 256, 0, stream>>>(
        ob, woT + (size_t)l * EE, bo + l * E_, xf, xf, M_, E_, E_);
    k_ln_bf<<<M_, 256, 0, stream>>>(xf, ln2g + l * E_, ln2b + l * E_, hb);
    k_gemm_256<1, true, 0, 4><<<16 * (4 * E_ / 256), 512, 0, stream>>>(
        hb, w1T + (size_t)l * 4 * EE, b1 + (size_t)l * 4 * E_, mh, 4 * E_, E_, E_);
    // MLP2: split-K=4 -> bf16 partials -> fused reduce(+b2+residual) + next-layer LN
    k_gemm_256<1, false, 2, 4><<<256, 512, 0, stream>>>(
        mh, w2T + (size_t)l * 4 * EE, nullptr, p2, E_, E_, 4 * E_);
    const float* ng = (l + 1 < L_) ? (ln1g + (size_t)(l + 1) * E_) : lnfg;
    const float* nb = (l + 1 < L_) ? (ln1b + (size_t)(l + 1) * E_) : lnfb;
    k_red4ln<<<M_, 256, 0, stream>>>(p2, b2 + l * E_, xf, ng, nb, hb);
  }
  // hb now holds lnf(x)
  if (lm_fast)
    k_gemm_256<0, false, 1, 4><<<16 * (V_ / 256), 512, 0, stream>>>(
        hb, wlmT, blm, (float*)d_out, V_, E_, E_);
  else
    k_gemm_bf<0, false, false><<<dim3(32, V_ / 128), 256, 0, stream>>>(
        hb, Wlm, blm, nullptr, (float*)d_out, M_, V_, E_);
}

// Round 18
// 2342.734 us; speedup vs baseline: 1.0612x; 1.0053x over previous
//
#include <hip/hip_runtime.h>
#include <math.h>

#define L_ 8
#define H_ 16
#define E_ 1024
#define V_ 32000
#define B_ 4
#define T_ 1024
#define HS_ 64
#define M_ 4096   // B*T
#define QKVS_ 3072  // fused qkv row stride

typedef __attribute__((ext_vector_type(8))) short short8;
typedef __attribute__((ext_vector_type(4))) float f32x4;

__device__ __forceinline__ unsigned short f2bf(float f) {
  unsigned int u = __builtin_bit_cast(unsigned int, f);
  u += 0x7fffu + ((u >> 16) & 1u);          // RNE
  return (unsigned short)(u >> 16);
}
__device__ __forceinline__ float bf2f(unsigned short u) {
  unsigned int v = ((unsigned int)u) << 16;
  return __builtin_bit_cast(float, v);
}

// ---------------------------------------------------------------- embed (fp32 x)
__global__ __launch_bounds__(256) void k_embed(
    const int* __restrict__ idx, const float* __restrict__ tok,
    const float* __restrict__ pos, float* __restrict__ x) {
  int bt = blockIdx.x;
  int t  = bt & (T_ - 1);
  int token = idx[bt];
  const float4* te = (const float4*)(tok + (size_t)token * E_);
  const float4* pe = (const float4*)(pos + (size_t)t * E_);
  float4* xo = (float4*)(x + (size_t)bt * E_);
  int i = threadIdx.x;
  float4 a = te[i], b = pe[i];
  xo[i] = make_float4(a.x + b.x, a.y + b.y, a.z + b.z, a.w + b.w);
}

// ---------------------------------------------------------------- weight transpose+convert (vectorized)
__global__ __launch_bounds__(256) void k_wt(
    const float* __restrict__ W, unsigned short* __restrict__ WT,
    int K, int N, size_t ss, size_t ds) {
  __shared__ unsigned short t[64][68];
  const float* Ws = W + (size_t)blockIdx.z * ss;
  unsigned short* Wd = WT + (size_t)blockIdx.z * ds;
  int n0 = blockIdx.x * 64, k0 = blockIdx.y * 64;
  int tid = threadIdx.x;
  int c4 = (tid & 15) * 4, r16 = tid >> 4;
  #pragma unroll
  for (int i = 0; i < 4; ++i) {
    int kr = i * 16 + r16;
    float4 v = *(const float4*)&Ws[(size_t)(k0 + kr) * N + n0 + c4];
    ushort4 pk;
    pk.x = f2bf(v.x); pk.y = f2bf(v.y); pk.z = f2bf(v.z); pk.w = f2bf(v.w);
    *(ushort4*)&t[kr][c4] = pk;
  }
  __syncthreads();
  #pragma unroll
  for (int i = 0; i < 4; ++i) {
    int nr = i * 16 + r16;
    ushort4 o;
    o.x = t[c4 + 0][nr]; o.y = t[c4 + 1][nr];
    o.z = t[c4 + 2][nr]; o.w = t[c4 + 3][nr];
    *(ushort4*)&Wd[(size_t)(n0 + nr) * K + k0 + c4] = o;
  }
}

// ---------------------------------------------------------------- layernorm (fp32 in, bf16 out)
__device__ __forceinline__ float blk_sum256(float v, float* red) {
  #pragma unroll
  for (int o = 1; o < 64; o <<= 1) v += __shfl_xor(v, o);
  int wid = threadIdx.x >> 6, lane = threadIdx.x & 63;
  if (lane == 0) red[wid] = v;
  __syncthreads();
  v = red[0] + red[1] + red[2] + red[3];
  __syncthreads();
  return v;
}

__global__ __launch_bounds__(256) void k_ln_bf(
    const float* __restrict__ X, const float* __restrict__ g,
    const float* __restrict__ b, unsigned short* __restrict__ Y) {
  __shared__ float red[4];
  int row = blockIdx.x;
  int i = threadIdx.x;
  float4 xv = ((const float4*)(X + (size_t)row * E_))[i];
  float s = xv.x + xv.y + xv.z + xv.w;
  s = blk_sum256(s, red);
  float mean = s * (1.0f / E_);
  float dx = xv.x - mean, dy = xv.y - mean, dz = xv.z - mean, dw = xv.w - mean;
  float vs = dx*dx + dy*dy + dz*dz + dw*dw;
  vs = blk_sum256(vs, red);
  float rstd = rsqrtf(vs * (1.0f / E_) + 1e-5f);
  float4 gv = ((const float4*)g)[i];
  float4 bv = ((const float4*)b)[i];
  ushort4 o;
  o.x = f2bf(dx * rstd * gv.x + bv.x);
  o.y = f2bf(dy * rstd * gv.y + bv.y);
  o.z = f2bf(dz * rstd * gv.z + bv.z);
  o.w = f2bf(dw * rstd * gv.w + bv.w);
  ((ushort4*)(Y + (size_t)row * E_))[i] = o;
}

// ---------------------------------------------------------------- fused split-K reduce + residual + next-LN
__global__ __launch_bounds__(256) void k_red4ln(
    const unsigned short* __restrict__ p, const float* __restrict__ bias,
    float* __restrict__ xf, const float* __restrict__ g,
    const float* __restrict__ b, unsigned short* __restrict__ hb) {
  __shared__ float red[4];
  const int ME = M_ * E_;
  int row = blockIdx.x;
  int tid = threadIdx.x;
  int i = row * E_ + tid * 4;
  ushort4 a  = *(const ushort4*)(p + i);
  ushort4 b2 = *(const ushort4*)(p + ME + i);
  ushort4 c  = *(const ushort4*)(p + 2 * ME + i);
  ushort4 d  = *(const ushort4*)(p + 3 * ME + i);
  float4 bv = *(const float4*)(bias + tid * 4);
  float4 x  = *(float4*)(xf + i);
  x.x += bf2f(a.x) + bf2f(b2.x) + bf2f(c.x) + bf2f(d.x) + bv.x;
  x.y += bf2f(a.y) + bf2f(b2.y) + bf2f(c.y) + bf2f(d.y) + bv.y;
  x.z += bf2f(a.z) + bf2f(b2.z) + bf2f(c.z) + bf2f(d.z) + bv.z;
  x.w += bf2f(a.w) + bf2f(b2.w) + bf2f(c.w) + bf2f(d.w) + bv.w;
  *(float4*)(xf + i) = x;
  float s = x.x + x.y + x.z + x.w;
  s = blk_sum256(s, red);
  float mean = s * (1.0f / E_);
  float dx = x.x - mean, dy = x.y - mean, dz = x.z - mean, dw = x.w - mean;
  float vs = dx*dx + dy*dy + dz*dz + dw*dw;
  vs = blk_sum256(vs, red);
  float rstd = rsqrtf(vs * (1.0f / E_) + 1e-5f);
  float4 gv = ((const float4*)g)[tid];
  float4 lb = ((const float4*)b)[tid];
  ushort4 o;
  o.x = f2bf(dx * rstd * gv.x + lb.x);
  o.y = f2bf(dy * rstd * gv.y + lb.y);
  o.z = f2bf(dz * rstd * gv.z + lb.z);
  o.w = f2bf(dw * rstd * gv.w + lb.w);
  ((ushort4*)(hb + (size_t)row * E_))[tid] = o;
}

#define GLDS(src, dst) __builtin_amdgcn_global_load_lds( \
    (const __attribute__((address_space(1))) void*)(src), \
    (__attribute__((address_space(3))) void*)(dst), 16, 0, 0)

#define BAR() do { asm volatile("" ::: "memory"); __builtin_amdgcn_s_barrier(); \
                   asm volatile("" ::: "memory"); } while (0)

// ---------------------------------------------------------------- 256xBN 8-phase bf16 GEMM (BK=64)
// Split counted waits: tile-end vmcnt(4) covers {B-hi,A-lo}; P0-end vmcnt(4)
// covers A-hi (2.5 phases old). Tail tiles drain with vmcnt(0).
// DEC: 0 = m-fastest, 1 = LM head (msub8-fastest), 2 = split-K=4 partials.
template<int OT, bool RELU, int DEC, int NF>
__global__ __launch_bounds__(512, 2) void k_gemm_256(
    const unsigned short* __restrict__ A, const unsigned short* __restrict__ BT,
    const float* __restrict__ bias, void* __restrict__ Cout, int N, int K, int Kstr) {
  constexpr int BUFA = 16384;        // 256*64
  constexpr int BUFB = NF * 4096;    // BN*64
  constexpr int BN = NF * 64;
  __shared__ __attribute__((aligned(16))) unsigned short As[2 * BUFA];
  __shared__ __attribute__((aligned(16))) unsigned short Bs[2 * BUFB];
  int tid = threadIdx.x;
  int lane = tid & 63, w = tid >> 6;           // 8 waves
  int lr = lane & 15, lq = (lane >> 4) & 3;
  int wm = w >> 2, wn = w & 3;                 // 2 x 4 wave grid

  // bijective XCD swizzle (m204)
  int nwg = gridDim.x, orig = blockIdx.x;
  int qq = nwg >> 3, rr = nwg & 7;
  int xcd = orig & 7, lid = orig >> 3;
  int wg = (xcd < rr ? xcd * (qq + 1) : rr * (qq + 1) + (xcd - rr) * qq) + lid;
  int m0, n0, kofs = 0;
  size_t cofs = 0;
  if constexpr (DEC == 0) { m0 = (wg & 15) * 256; n0 = (wg >> 4) * BN; }
  else if constexpr (DEC == 1) {
    int nbn = N / BN;
    int msub = wg & 7;
    int rest = wg >> 3;
    int nb = rest % nbn;
    int msup = rest / nbn;
    m0 = (msup * 8 + msub) * 256;
    n0 = nb * BN;
  } else {
    int inner = wg & 63;
    m0 = (inner & 15) * 256; n0 = (inner >> 4) * BN;
    int ks = wg >> 6;
    kofs = ks * K;
    cofs = (size_t)ks * M_ * (size_t)N;
  }

  // staging: chunk swizzle c8_src = (lane&7) ^ (lane>>3); dest linear
  int srow = w * 8 + (lane >> 3);
  int skoff = ((lane & 7) ^ (lane >> 3)) * 8;
  const unsigned short* aS = A + (size_t)(m0 + srow) * Kstr + kofs + skoff;
  const unsigned short* bS = BT + (size_t)(n0 + srow) * Kstr + kofs + skoff;

#define STG_A1(bo, g, tt) GLDS(aS + (size_t)((g) * 64) * Kstr + (tt) * 64, \
                               &As[(bo) + (((g) * 64) << 6) + (w << 9)])
#define STG_B1(bo, g, tt) GLDS(bS + (size_t)((g) * 64) * Kstr + (tt) * 64, \
                               &Bs[(bo) + (((g) * 64) << 6) + (w << 9)])
#define LDA_(dst, mh, ks) { _Pragma("unroll") for (int m_ = 0; m_ < 4; ++m_) \
  dst[m_] = *(const short8*)&As[soA + ((wm * 128 + (mh) * 64 + m_ * 16 + lr) << 6) + ((((ks) * 4 + lq) ^ (lr & 7)) << 3)]; }
#define LDB_(dst, ks) { _Pragma("unroll") for (int n_ = 0; n_ < NF; ++n_) \
  dst[n_] = *(const short8*)&Bs[soB + ((wn * (16 * NF) + n_ * 16 + lr) << 6) + ((((ks) * 4 + lq) ^ (lr & 7)) << 3)]; }
#define MMA(afr, mofs) do { __builtin_amdgcn_s_setprio(1); \
  _Pragma("unroll") for (int m_ = 0; m_ < 4; ++m_) { \
    _Pragma("unroll") for (int n_ = 0; n_ < NF; ++n_) \
      acc[(mofs) + m_][n_] = __builtin_amdgcn_mfma_f32_16x16x32_bf16(afr[m_], bfr[n_], acc[(mofs) + m_][n_], 0, 0, 0); } \
  __builtin_amdgcn_s_setprio(0); } while (0)

  f32x4 acc[8][NF] = {};
  const int NT = K >> 6;

  // prologue: tile0 full (4+NF loads) + B(t1) g0,g1 -> vmcnt(2)
  #pragma unroll
  for (int g = 0; g < 4; ++g) STG_A1(0, g, 0);
  #pragma unroll
  for (int g = 0; g < NF; ++g) STG_B1(0, g, 0);
  if (NT > 1) {
    STG_B1(BUFB, 0, 1); STG_B1(BUFB, 1, 1);
    asm volatile("s_waitcnt vmcnt(2)" ::: "memory");
  } else {
    asm volatile("s_waitcnt vmcnt(0)" ::: "memory");
  }
  BAR();

  for (int t = 0; t < NT; ++t) {
    const int soA = (t & 1) * BUFA, soB = (t & 1) * BUFB;
    const int nbA = ((t + 1) & 1) * BUFA, nbB = ((t + 1) & 1) * BUFB;
    short8 af0[4], af1[4], bfr[NF];
    // ---- P0: stage B-hi(t+1) -> idle
    LDA_(af0, 0, 0);
    LDB_(bfr, 0);
    if (t + 1 < NT) {
      STG_B1(nbB, 2, t + 1);
      if constexpr (NF == 4) STG_B1(nbB, 3, t + 1);
    }
    BAR(); MMA(af0, 0);
    // P0-end counted wait: A-hi(t) was issued at P2 of t-1 (2.5 phases ago);
    // steady-state leaves <=4 younger loads in flight. Tail: fully drained already.
    if (t > 0 && t + 1 < NT) { asm volatile("s_waitcnt vmcnt(4)" ::: "memory"); }
    BAR();
    // ---- P1: stage A-lo(t+1) -> idle
    LDA_(af1, 1, 0);
    if (t + 1 < NT) { STG_A1(nbA, 0, t + 1); STG_A1(nbA, 1, t + 1); }
    BAR(); MMA(af1, 4); BAR();
    // ---- P2: stage A-hi(t+1) -> idle
    LDA_(af0, 0, 1);
    LDB_(bfr, 1);
    if (t + 1 < NT) { STG_A1(nbA, 2, t + 1); STG_A1(nbA, 3, t + 1); }
    BAR(); MMA(af0, 0); BAR();
    // ---- P3: stage B-lo(t+2) -> current buffer B region (dead after P2)
    LDA_(af1, 1, 1);
    if (t + 2 < NT) { STG_B1(soB, 0, t + 2); STG_B1(soB, 1, t + 2); }
    BAR(); MMA(af1, 4);
    // tile-end counted wait: needs B-hi(t+1)+A-lo(t+1) (3-4 phases old);
    // A-hi(t+1) deferred to next tile's P0-end. Tail tiles drain fully.
    if (t + 2 < NT)      { asm volatile("s_waitcnt vmcnt(4)" ::: "memory"); }
    else                 { asm volatile("s_waitcnt vmcnt(0)" ::: "memory"); }
    BAR();
  }

  #pragma unroll
  for (int m = 0; m < 8; ++m) {
    #pragma unroll
    for (int n = 0; n < NF; ++n) {
      int col = n0 + wn * (16 * NF) + n * 16 + lr;
      float bv = bias ? bias[col] : 0.0f;
      #pragma unroll
      for (int i = 0; i < 4; ++i) {
        size_t row = (size_t)(m0 + wm * 128 + m * 16 + lq * 4 + i);
        float v = acc[m][n][i] + bv;
        if (RELU) v = fmaxf(v, 0.0f);
        if (OT == 0) ((float*)Cout)[cofs + row * N + col] = v;
        else ((unsigned short*)Cout)[cofs + row * N + col] = f2bf(v);
      }
    }
  }
#undef STG_A1
#undef STG_B1
#undef LDA_
#undef LDB_
#undef MMA
}

// ---------------------------------------------------------------- bf16 TN MFMA GEMM (2-phase, BN<=128)
template<int BN, int OT, bool RELU, bool RES>
__global__ __launch_bounds__(256) void k_gemm_tn(
    const unsigned short* __restrict__ A, const unsigned short* __restrict__ BT,
    const float* __restrict__ bias, const float* __restrict__ R,
    void* __restrict__ Cout, int M, int N, int K) {
  constexpr int NF = BN / 32;
  __shared__ __attribute__((aligned(16))) unsigned short As[128 * 64];
  __shared__ __attribute__((aligned(16))) unsigned short Bs[BN * 64];
  int tid = threadIdx.x;
  int lane = tid & 63, w = tid >> 6;
  int lr = lane & 15, lq = lane >> 4;
  int m0 = blockIdx.x * 128, n0 = blockIdx.y * BN;
  int wr = (w >> 1) * 64, wc = (w & 1) * (BN / 2);

  int srow = w * 8 + (lane >> 3);
  int skoff = ((lane & 7) ^ (lane >> 3)) * 8;
  const unsigned short* a0 = A + (size_t)(m0 + srow) * K + skoff;
  const unsigned short* b0 = BT + (size_t)(n0 + srow) * K + skoff;

  f32x4 acc[4][NF] = {};

  for (int k0 = 0; k0 < K; k0 += 64) {
    __syncthreads();
    #pragma unroll
    for (int j = 0; j < 4; ++j)
      __builtin_amdgcn_global_load_lds(
          (const __attribute__((address_space(1))) void*)(a0 + (size_t)(j * 32) * K + k0),
          (__attribute__((address_space(3))) void*)(As + j * 2048 + w * 512), 16, 0, 0);
    #pragma unroll
    for (int j = 0; j < NF; ++j)
      __builtin_amdgcn_global_load_lds(
          (const __attribute__((address_space(1))) void*)(b0 + (size_t)(j * 32) * K + k0),
          (__attribute__((address_space(3))) void*)(Bs + j * 2048 + w * 512), 16, 0, 0);
    __syncthreads();
    short8 af[4][2], bf[NF][2];
    #pragma unroll
    for (int m = 0; m < 4; ++m)
      #pragma unroll
      for (int ks = 0; ks < 2; ++ks)
        af[m][ks] = *(const short8*)&As[(wr + m * 16 + lr) * 64 + (((ks * 4 + lq) ^ (lr & 7)) << 3)];
    #pragma unroll
    for (int n = 0; n < NF; ++n)
      #pragma unroll
      for (int ks = 0; ks < 2; ++ks)
        bf[n][ks] = *(const short8*)&Bs[(wc + n * 16 + lr) * 64 + (((ks * 4 + lq) ^ (lr & 7)) << 3)];
    #pragma unroll
    for (int ks = 0; ks < 2; ++ks)
      #pragma unroll
      for (int m = 0; m < 4; ++m)
        #pragma unroll
        for (int n = 0; n < NF; ++n)
          acc[m][n] = __builtin_amdgcn_mfma_f32_16x16x32_bf16(af[m][ks], bf[n][ks], acc[m][n], 0, 0, 0);
  }

  #pragma unroll
  for (int m = 0; m < 4; ++m) {
    #pragma unroll
    for (int n = 0; n < NF; ++n) {
      int col = n0 + wc + n * 16 + lr;
      float bv = bias ? bias[col] : 0.0f;
      #pragma unroll
      for (int i = 0; i < 4; ++i) {
        size_t row = (size_t)(m0 + wr + m * 16 + lq * 4 + i);
        float v = acc[m][n][i] + bv;
        if (RELU) v = fmaxf(v, 0.0f);
        if (RES)  v += R[row * N + col];
        if (OT == 0) ((float*)Cout)[row * N + col] = v;
        else ((unsigned short*)Cout)[row * N + col] = f2bf(v);
      }
    }
  }
}

// ---------------------------------------------------------------- legacy GEMM (fp32 B) for LM fallback
template<int OT, bool RELU, bool RES>
__global__ __launch_bounds__(256) void k_gemm_bf(
    const unsigned short* __restrict__ A, const float* __restrict__ W,
    const float* __restrict__ bias, const float* __restrict__ R,
    void* __restrict__ Cout, int M, int N, int K) {
  __shared__ unsigned short As[128][40];
  __shared__ unsigned short Bs[128][40];
  int tid = threadIdx.x;
  int lane = tid & 63, wid = tid >> 6;
  int m0 = blockIdx.x * 128, n0 = blockIdx.y * 128;
  int wr = (wid >> 1) * 64, wc = (wid & 1) * 64;
  f32x4 acc[4][4] = {};
  int a_row = tid >> 1, a_koff = (tid & 1) * 16;
  int b_nb = tid & 31, b_kb = (tid >> 5) * 4;
  int lr = lane & 15, lq = lane >> 4;
  for (int k0 = 0; k0 < K; k0 += 32) {
    const unsigned short* ap = A + (size_t)(m0 + a_row) * K + k0 + a_koff;
    uint4 av0 = *(const uint4*)ap;
    uint4 av1 = *(const uint4*)(ap + 8);
    float wv[4][4];
    #pragma unroll
    for (int dk = 0; dk < 4; ++dk) {
      const float* wrow = W + (size_t)(k0 + b_kb + dk) * N + n0 + b_nb;
      #pragma unroll
      for (int j = 0; j < 4; ++j) wv[j][dk] = wrow[32 * j];
    }
    __syncthreads();
    *(uint4*)&As[a_row][a_koff]     = av0;
    *(uint4*)&As[a_row][a_koff + 8] = av1;
    #pragma unroll
    for (int j = 0; j < 4; ++j) {
      ushort4 pk;
      pk.x = f2bf(wv[j][0]); pk.y = f2bf(wv[j][1]);
      pk.z = f2bf(wv[j][2]); pk.w = f2bf(wv[j][3]);
      *(ushort4*)&Bs[b_nb + 32 * j][b_kb] = pk;
    }
    __syncthreads();
    short8 af[4], bf[4];
    #pragma unroll
    for (int m = 0; m < 4; ++m) af[m] = *(const short8*)&As[wr + m * 16 + lr][lq * 8];
    #pragma unroll
    for (int n = 0; n < 4; ++n) bf[n] = *(const short8*)&Bs[wc + n * 16 + lr][lq * 8];
    #pragma unroll
    for (int m = 0; m < 4; ++m)
      #pragma unroll
      for (int n = 0; n < 4; ++n)
        acc[m][n] = __builtin_amdgcn_mfma_f32_16x16x32_bf16(af[m], bf[n], acc[m][n], 0, 0, 0);
  }
  #pragma unroll
  for (int m = 0; m < 4; ++m) {
    #pragma unroll
    for (int n = 0; n < 4; ++n) {
      int col = n0 + wc + n * 16 + lr;
      float bv = bias ? bias[col] : 0.0f;
      #pragma unroll
      for (int i = 0; i < 4; ++i) {
        size_t row = (size_t)(m0 + wr + m * 16 + lq * 4 + i);
        float v = acc[m][n][i] + bv;
        if (RELU) v = fmaxf(v, 0.0f);
        if (RES)  v += R[row * N + col];
        if (OT == 0) ((float*)Cout)[row * N + col] = v;
        else ((unsigned short*)Cout)[row * N + col] = f2bf(v);
      }
    }
  }
}

// ---------------------------------------------------------------- flash attention (bf16 MFMA, KVBLK=128)
// Load-balanced 1-D grid of 512: block f -> (qt,bh) such that co-resident
// pairs (f, f+256) have qt + qt' = 7 (uniform ~9 tile-units per CU).
__global__ __launch_bounds__(256) void k_fattn(
    const unsigned short* __restrict__ QKV, unsigned short* __restrict__ O) {
  __shared__ unsigned short Ks[128][72];     // [k][d] 144B rows
  __shared__ unsigned short Vs[64][136];     // [d][k] transposed, 272B rows
  __shared__ unsigned short Pl[4][32][136];  // per-wave P transpose
  int tid = threadIdx.x;
  int lane = tid & 63, wid = tid >> 6;
  int lr = lane & 15, lq = lane >> 4;
  int f = blockIdx.x;
  int half = f >> 8, rm = f & 255;
  int qt = half ? 7 - (rm & 3) : (rm & 3);
  int bh = rm >> 2;
  int b = bh >> 4, h = bh & 15;
  size_t base = ((size_t)b * T_) * QKVS_ + h * HS_;
  int q0w = qt * 128 + wid * 32;

  short8 qf[2][2];
  #pragma unroll
  for (int g = 0; g < 2; ++g)
    #pragma unroll
    for (int s = 0; s < 2; ++s)
      qf[g][s] = *(const short8*)(QKV + base + (size_t)(q0w + g * 16 + lr) * QKVS_ + s * 32 + lq * 8);

  f32x4 o_acc[2][4] = {};
  float mrun[2][4], lrun[2][4];
  #pragma unroll
  for (int g = 0; g < 2; ++g)
    #pragma unroll
    for (int i = 0; i < 4; ++i) { mrun[g][i] = -1e30f; lrun[g][i] = 0.0f; }
  const float sc = 0.03125f * 1.44269504f;
  int r = tid >> 2, cc = (tid & 3) * 16;
  int ntiles = qt + 1;

  uint4 kA0, kA1, kB0, kB1, vA0, vA1, vB0, vB1;
  {
    const unsigned short* kp = QKV + base + 1024 + (size_t)r * QKVS_ + cc;
    kA0 = *(const uint4*)kp; kA1 = *(const uint4*)(kp + 8);
    vA0 = *(const uint4*)(kp + 1024); vA1 = *(const uint4*)(kp + 1032);
    const unsigned short* kp2 = kp + (size_t)64 * QKVS_;
    kB0 = *(const uint4*)kp2; kB1 = *(const uint4*)(kp2 + 8);
    vB0 = *(const uint4*)(kp2 + 1024); vB1 = *(const uint4*)(kp2 + 1032);
  }

  for (int t = 0; t < ntiles; ++t) {
    __syncthreads();                         // prev tile's LDS reads done
    *(uint4*)&Ks[r][cc] = kA0;
    *(uint4*)&Ks[r][cc + 8] = kA1;
    *(uint4*)&Ks[64 + r][cc] = kB0;
    *(uint4*)&Ks[64 + r][cc + 8] = kB1;
    unsigned short vt[16];
    *(uint4*)&vt[0] = vA0; *(uint4*)&vt[8] = vA1;
    #pragma unroll
    for (int j = 0; j < 16; ++j) Vs[cc + j][r] = vt[j];
    *(uint4*)&vt[0] = vB0; *(uint4*)&vt[8] = vB1;
    #pragma unroll
    for (int j = 0; j < 16; ++j) Vs[cc + j][64 + r] = vt[j];
    __syncthreads();                         // staging visible
    if (t + 1 < ntiles) {                    // T14: hide next-tile HBM under compute
      const unsigned short* kp = QKV + base + 1024 + (size_t)((t + 1) * 128 + r) * QKVS_ + cc;
      kA0 = *(const uint4*)kp; kA1 = *(const uint4*)(kp + 8);
      vA0 = *(const uint4*)(kp + 1024); vA1 = *(const uint4*)(kp + 1032);
      const unsigned short* kp2 = kp + (size_t)64 * QKVS_;
      kB0 = *(const uint4*)kp2; kB1 = *(const uint4*)(kp2 + 8);
      vB0 = *(const uint4*)(kp2 + 1024); vB1 = *(const uint4*)(kp2 + 1032);
    }

    bool diag = (t == qt);
    float p[2][8][4];
    __builtin_amdgcn_s_setprio(1);           // T5: favor QK^T MFMA cluster
    #pragma unroll
    for (int nt = 0; nt < 8; ++nt) {
      f32x4 s0 = {}, s1 = {};
      #pragma unroll
      for (int s = 0; s < 2; ++s) {
        short8 kf = *(const short8*)&Ks[nt * 16 + lr][s * 32 + lq * 8];
        s0 = __builtin_amdgcn_mfma_f32_16x16x32_bf16(qf[0][s], kf, s0, 0, 0, 0);
        s1 = __builtin_amdgcn_mfma_f32_16x16x32_bf16(qf[1][s], kf, s1, 0, 0, 0);
      }
      #pragma unroll
      for (int i = 0; i < 4; ++i) {
        float v0 = s0[i] * sc, v1 = s1[i] * sc;
        if (diag) {
          int col = t * 128 + nt * 16 + lr;
          if (col > q0w + lq * 4 + i) v0 = -1e30f;
          if (col > q0w + 16 + lq * 4 + i) v1 = -1e30f;
        }
        p[0][nt][i] = v0;
        p[1][nt][i] = v1;
      }
    }
    __builtin_amdgcn_s_setprio(0);
    #pragma unroll
    for (int g = 0; g < 2; ++g)
      #pragma unroll
      for (int i = 0; i < 4; ++i) {
        float v = fmaxf(fmaxf(fmaxf(p[g][0][i], p[g][1][i]), fmaxf(p[g][2][i], p[g][3][i])),
                        fmaxf(fmaxf(p[g][4][i], p[g][5][i]), fmaxf(p[g][6][i], p[g][7][i])));
        #pragma unroll
        for (int o = 1; o < 16; o <<= 1) v = fmaxf(v, __shfl_xor(v, o));
        if (v > mrun[g][i] + 10.0f) {        // T13 defer-max
          float corr = __builtin_amdgcn_exp2f(mrun[g][i] - v);
          mrun[g][i] = v;
          lrun[g][i] *= corr;
          #pragma unroll
          for (int dn = 0; dn < 4; ++dn) o_acc[g][dn][i] *= corr;
        }
        float mn = mrun[g][i];
        float ps = 0.0f;
        #pragma unroll
        for (int nt = 0; nt < 8; ++nt) {
          float pe = __builtin_amdgcn_exp2f(p[g][nt][i] - mn);
          p[g][nt][i] = pe;
          ps += pe;
        }
        lrun[g][i] += ps;
      }
    // P -> per-wave LDS transpose; intra-wave DS ordering suffices (no barrier)
    #pragma unroll
    for (int g = 0; g < 2; ++g)
      #pragma unroll
      for (int nt = 0; nt < 8; ++nt)
        #pragma unroll
        for (int i = 0; i < 4; ++i)
          Pl[wid][g * 16 + lq * 4 + i][nt * 16 + lr] = f2bf(p[g][nt][i]);

    __builtin_amdgcn_s_setprio(1);           // T5: favor PV MFMA cluster
    #pragma unroll
    for (int s = 0; s < 4; ++s) {
      short8 pa0 = *(const short8*)&Pl[wid][lr][s * 32 + lq * 8];
      short8 pa1 = *(const short8*)&Pl[wid][16 + lr][s * 32 + lq * 8];
      #pragma unroll
      for (int dn = 0; dn < 4; ++dn) {
        short8 vf = *(const short8*)&Vs[dn * 16 + lr][s * 32 + lq * 8];
        o_acc[0][dn] = __builtin_amdgcn_mfma_f32_16x16x32_bf16(pa0, vf, o_acc[0][dn], 0, 0, 0);
        o_acc[1][dn] = __builtin_amdgcn_mfma_f32_16x16x32_bf16(pa1, vf, o_acc[1][dn], 0, 0, 0);
      }
    }
    __builtin_amdgcn_s_setprio(0);
  }

  #pragma unroll
  for (int g = 0; g < 2; ++g)
    #pragma unroll
    for (int i = 0; i < 4; ++i) {
      float v = lrun[g][i];
      #pragma unroll
      for (int o = 1; o < 16; o <<= 1) v += __shfl_xor(v, o);
      lrun[g][i] = 1.0f / v;
    }
  #pragma unroll
  for (int g = 0; g < 2; ++g)
    #pragma unroll
    for (int dn = 0; dn < 4; ++dn)
      #pragma unroll
      for (int i = 0; i < 4; ++i) {
        size_t row = (size_t)(b * T_) + q0w + g * 16 + lq * 4 + i;
        O[row * E_ + h * HS_ + dn * 16 + lr] = f2bf(o_acc[g][dn][i] * lrun[g][i]);
      }
}

// ---------------------------------------------------------------- launch
extern "C" void kernel_launch(void* const* d_in, const int* in_sizes, int n_in,
                              void* d_out, int out_size, void* d_ws, size_t ws_size,
                              hipStream_t stream) {
  const int*   idx  = (const int*)d_in[0];
  const float* tok  = (const float*)d_in[1];
  const float* pos  = (const float*)d_in[2];
  const float* ln1g = (const float*)d_in[3];
  const float* ln1b = (const float*)d_in[4];
  const float* Wq   = (const float*)d_in[5];
  const float* Wk   = (const float*)d_in[6];
  const float* Wv   = (const float*)d_in[7];
  const float* Wo   = (const float*)d_in[8];
  const float* bo   = (const float*)d_in[9];
  const float* ln2g = (const float*)d_in[10];
  const float* ln2b = (const float*)d_in[11];
  const float* W1   = (const float*)d_in[12];
  const float* b1   = (const float*)d_in[13];
  const float* W2   = (const float*)d_in[14];
  const float* b2   = (const float*)d_in[15];
  const float* lnfg = (const float*)d_in[16];
  const float* lnfb = (const float*)d_in[17];
  const float* Wlm  = (const float*)d_in[18];
  const float* blm  = (const float*)d_in[19];

  char* scr = (char*)d_out;
  const size_t MB = 1024 * 1024;
  float*          xf    = (float*)(scr);                      // 16MB
  unsigned short* qkvb  = (unsigned short*)(scr + 16 * MB);   // 24MB
  unsigned short* ob    = (unsigned short*)(scr + 40 * MB);   // 8MB
  unsigned short* mh    = (unsigned short*)(scr + 48 * MB);   // 32MB
  unsigned short* wqkvT = (unsigned short*)(scr + 80 * MB);   // 48MB
  unsigned short* woT   = (unsigned short*)(scr + 128 * MB);  // 16MB
  unsigned short* w1T   = (unsigned short*)(scr + 144 * MB);  // 64MB
  unsigned short* w2T   = (unsigned short*)(scr + 208 * MB);  // 64MB
  unsigned short* p2    = (unsigned short*)(scr + 280 * MB);  // 32MB split-K bf16 partials
  unsigned short* hb    = (unsigned short*)d_ws;              // 8MB
  unsigned short* wlmT  = (unsigned short*)((char*)d_ws + 8 * MB); // 65.5MB
  const size_t EE = (size_t)E_ * E_;
  bool lm_fast = ws_size >= 8 * MB + (size_t)V_ * E_ * 2 + 1024;

  k_embed<<<M_, 256, 0, stream>>>(idx, tok, pos, xf);

  k_wt<<<dim3(16, 16, L_), 256, 0, stream>>>(Wq, wqkvT,          E_, E_, EE, 3 * EE);
  k_wt<<<dim3(16, 16, L_), 256, 0, stream>>>(Wk, wqkvT + EE,     E_, E_, EE, 3 * EE);
  k_wt<<<dim3(16, 16, L_), 256, 0, stream>>>(Wv, wqkvT + 2 * EE, E_, E_, EE, 3 * EE);
  k_wt<<<dim3(16, 16, L_), 256, 0, stream>>>(Wo, woT,            E_, E_, EE, EE);
  k_wt<<<dim3(64, 16, L_), 256, 0, stream>>>(W1, w1T, E_, 4 * E_, 4 * EE, 4 * EE);
  k_wt<<<dim3(16, 64, L_), 256, 0, stream>>>(W2, w2T, 4 * E_, E_, 4 * EE, 4 * EE);
  if (lm_fast)
    k_wt<<<dim3(V_ / 64, 16, 1), 256, 0, stream>>>(Wlm, wlmT, E_, V_, 0, 0);

  // ln1 of layer 0; subsequent LNs: ln2 standalone, ln1(l+1)/lnf fused into k_red4ln
  k_ln_bf<<<M_, 256, 0, stream>>>(xf, ln1g, ln1b, hb);

  for (int l = 0; l < L_; ++l) {
    // QKV: 256x192 tile -> 256 blocks (full CU utilization)
    k_gemm_256<1, false, 0, 3><<<16 * (QKVS_ / 192), 512, 0, stream>>>(
        hb, wqkvT + (size_t)l * 3 * EE, nullptr, qkvb, QKVS_, E_, E_);
    k_fattn<<<512, 256, 0, stream>>>(qkvb, ob);
    k_gemm_tn<64, 0, false, true><<<dim3(32, 16), 256, 0, stream>>>(
        ob, woT + (size_t)l * EE, bo + l * E_, xf, xf, M_, E_, E_);
    k_ln_bf<<<M_, 256, 0, stream>>>(xf, ln2g + l * E_, ln2b + l * E_, hb);
    k_gemm_256<1, true, 0, 4><<<16 * (4 * E_ / 256), 512, 0, stream>>>(
        hb, w1T + (size_t)l * 4 * EE, b1 + (size_t)l * 4 * E_, mh, 4 * E_, E_, E_);
    // MLP2: split-K=4 -> bf16 partials -> fused reduce(+b2+residual) + next-layer LN
    k_gemm_256<1, false, 2, 4><<<256, 512, 0, stream>>>(
        mh, w2T + (size_t)l * 4 * EE, nullptr, p2, E_, E_, 4 * E_);
    const float* ng = (l + 1 < L_) ? (ln1g + (size_t)(l + 1) * E_) : lnfg;
    const float* nb = (l + 1 < L_) ? (ln1b + (size_t)(l + 1) * E_) : lnfb;
    k_red4ln<<<M_, 256, 0, stream>>>(p2, b2 + l * E_, xf, ng, nb, hb);
  }
  // hb now holds lnf(x)
  if (lm_fast)
    k_gemm_256<0, false, 1, 4><<<16 * (V_ / 256), 512, 0, stream>>>(
        hb, wlmT, blm, (float*)d_out, V_, E_, E_);
  else
    k_gemm_bf<0, false, false><<<dim3(32, V_ / 128), 256, 0, stream>>>(
        hb, Wlm, blm, nullptr, (float*)d_out, M_, V_, E_);
}